// Round 8
// baseline (379.517 us; speedup 1.0000x reference)
//
#include <hip/hip_runtime.h>
#include <hip/hip_bf16.h>

typedef unsigned short u16;
using u16x4 = __attribute__((ext_vector_type(4))) unsigned short;
using u16x8 = __attribute__((ext_vector_type(8))) unsigned short;
using u32x4 = __attribute__((ext_vector_type(4))) unsigned int;
using f32x4 = __attribute__((ext_vector_type(4))) float;
using bf16x8 = __attribute__((ext_vector_type(8))) __bf16;

#define TNG 64
#define TNN 16384
#define TNE 131072
#define TFN 256
#define TFE 64
#define TFG 128
// graphs are fixed-size: edge e -> graph e>>11, node n -> graph n>>8

__device__ __forceinline__ u16 f2bf(float f) {
    unsigned u = __float_as_uint(f);
    unsigned r = (u + 0x7FFFu + ((u >> 16) & 1u)) >> 16;
    return (u16)r;
}
__device__ __forceinline__ float b2f(u16 h) {
    return __uint_as_float(((unsigned)h) << 16);
}

// async global->LDS, 16B per lane (dest must be linear: base + lane*16)
__device__ __forceinline__ void gload_lds16(const u16* g, u16* l) {
    __builtin_amdgcn_global_load_lds(
        (const __attribute__((address_space(1))) void*)g,
        (__attribute__((address_space(3))) void*)l, 16, 0, 0);
}

// chunked XCD swizzle: nwg % 8 == 0 -> XCD k gets a contiguous work range
__device__ __forceinline__ int xcd_swz(int bid, int nwg) {
    return (nwg & 7) == 0 ? (bid & 7) * (nwg >> 3) + (bid >> 3) : bid;
}

// ---------------- setup: f32 -> bf16 cast ----------------

__global__ void cast_kernel(const float* __restrict__ in, u16* __restrict__ out, int n4) {
    int i = blockIdx.x * 256 + threadIdx.x;
    if (i >= n4) return;
    f32x4 v = *(const f32x4*)(in + (size_t)i * 4);
    u16x4 o;
    o.x = f2bf(v.x); o.y = f2bf(v.y); o.z = f2bf(v.z); o.w = f2bf(v.w);
    *(u16x4*)(out + (size_t)i * 4) = o;
}

// ---------------- weight transpose+cast via LDS 64x64 tiles (coalesced both sides) --
// out[n*Ksub + k] = (n < Nact) ? W[(r0+k)*Nin + n] : 0

struct PrepTab {
    const float* W[8];
    int out_off[8];   // u16 offset from ws base
    int Nin[8], Nact[8], r0[8], Ksub[8];
    int tile0[8];     // prefix sum of tile counts; tiles = (Npad/64)*(Ksub/64)
    int tkn[8];       // Ksub/64
};

__global__ __launch_bounds__(256) void prep_weights_kernel(PrepTab tab, u16* __restrict__ wsbase) {
    const int b = blockIdx.x;
    int i = 7;
#pragma unroll
    for (int j = 7; j > 0; --j)
        if (b < tab.tile0[j]) i = j - 1;
    const int loc = b - tab.tile0[i];
    const int tk = loc % tab.tkn[i];
    const int tn = loc / tab.tkn[i];
    const int kb = tk * 64, nb = tn * 64;
    const int Nin = tab.Nin[i], Nact = tab.Nact[i], r0 = tab.r0[i], Ksub = tab.Ksub[i];
    const float* W = tab.W[i];
    u16* outp = wsbase + tab.out_off[i];

    __shared__ float t[64][65];
    const int tid = threadIdx.x;
    const int nl = tid & 63;
    const bool nok = (nb + nl) < Nact;
#pragma unroll 4
    for (int kk = tid >> 6; kk < 64; kk += 4) {
        float v = nok ? W[(size_t)(r0 + kb + kk) * Nin + nb + nl] : 0.0f;
        t[kk][nl] = v;
    }
    __syncthreads();
    const int kl = tid & 63;
#pragma unroll 4
    for (int nn = tid >> 6; nn < 64; nn += 4)
        outp[(size_t)(nb + nn) * Ksub + kb + kl] = f2bf(t[kl][nn]);
}

// ---------------- 256x256-tile bf16 MFMA GEMM (8 waves, counted-vmcnt pipeline) ----
// Same proven schedule as the 128 kernel: 3 LDS buffers, depth-2 prefetch, one raw
// s_barrier per K-step, in-loop vmcnt(4). Per K-step: 32 MFMA/wave, 4.2 MFLOP/block.
// Bank swizzle identical (slot ^ ((row>>1)&3), both sides).

template <int K, int NXSH, bool RELU, bool OUT_BF16>
__global__ __launch_bounds__(512) void gemm_bt256_kernel(
    const u16* __restrict__ A, const u16* __restrict__ Bt,
    const float* __restrict__ bias, void* __restrict__ Cv,
    int Nout, int ldc) {
    constexpr int NT = K / 32;
    __shared__ u16 As[3][8192];
    __shared__ u16 Bs[3][8192];
    const int w = xcd_swz(blockIdx.x, gridDim.x);
    const int bxi = w & ((1 << NXSH) - 1);
    const int byi = w >> NXSH;
    const int tid = threadIdx.x;
    const int wave = tid >> 6, lane = tid & 63;
    const int wm = wave >> 2, wn = wave & 3;        // 2 x 4 waves -> 128x64 each
    const size_t brow = (size_t)byi * 256;
    const size_t bcol = (size_t)bxi * 256;
    const int srow = tid >> 2;                      // 0..127
    const int qsrc = (tid & 3) ^ ((srow >> 1) & 3); // swizzled source slot
    const u16* aSrc = A + (brow + srow) * (size_t)K + qsrc * 8;
    const u16* bSrc = Bt + (bcol + srow) * (size_t)K + qsrc * 8;
    const size_t stepRows = (size_t)128 * K;

    auto stage = [&](int t, int buf) {
        const int k0 = t * 32;
        gload_lds16(aSrc + k0, &As[buf][tid * 8]);
        gload_lds16(aSrc + stepRows + k0, &As[buf][tid * 8 + 4096]);
        gload_lds16(bSrc + k0, &Bs[buf][tid * 8]);
        gload_lds16(bSrc + stepRows + k0, &Bs[buf][tid * 8 + 4096]);
    };

    f32x4 acc[8][4] = {};

    stage(0, 0);
    stage(1, 1);
#pragma unroll
    for (int t = 0; t < NT; ++t) {
        const int cur = t % 3;
        if (t + 1 < NT) asm volatile("s_waitcnt vmcnt(4)" ::: "memory");
        else            asm volatile("s_waitcnt vmcnt(0)" ::: "memory");
        __builtin_amdgcn_s_barrier();
        if (t + 2 < NT) stage(t + 2, (t + 2) % 3);
        bf16x8 af[8], bfv[4];
#pragma unroll
        for (int m = 0; m < 8; ++m) {
            const int row = wm * 128 + m * 16 + (lane & 15);
            const int slot = (lane >> 4) ^ ((row >> 1) & 3);
            af[m] = *(const bf16x8*)&As[cur][row * 32 + slot * 8];
        }
#pragma unroll
        for (int n = 0; n < 4; ++n) {
            const int row = wn * 64 + n * 16 + (lane & 15);
            const int slot = (lane >> 4) ^ ((row >> 1) & 3);
            bfv[n] = *(const bf16x8*)&Bs[cur][row * 32 + slot * 8];
        }
#pragma unroll
        for (int m = 0; m < 8; ++m)
#pragma unroll
            for (int n = 0; n < 4; ++n)
                acc[m][n] = __builtin_amdgcn_mfma_f32_16x16x32_bf16(af[m], bfv[n], acc[m][n], 0, 0, 0);
    }

    const int rowSub = wm * 128 + (lane >> 4) * 4;
#pragma unroll
    for (int n = 0; n < 4; ++n) {
        const int col = (int)bcol + wn * 64 + n * 16 + (lane & 15);
        if (col >= Nout) continue;
        const float bv = bias ? bias[col] : 0.0f;
#pragma unroll
        for (int m = 0; m < 8; ++m) {
#pragma unroll
            for (int i = 0; i < 4; ++i) {
                float v = acc[m][n][i] + bv;
                if (RELU) v = fmaxf(v, 0.0f);
                size_t off = (brow + rowSub + m * 16 + i) * (size_t)ldc + col;
                if (OUT_BF16) ((u16*)Cv)[off] = f2bf(v);
                else ((float*)Cv)[off] = v;
            }
        }
    }
}

// ---------------- 128-tile GEMM (kept for emb head, N=64) --------------------------

template <int K, int NXSH, bool RELU, bool OUT_BF16>
__global__ __launch_bounds__(256) void gemm_bt_kernel(
    const u16* __restrict__ A, const u16* __restrict__ Bt,
    const float* __restrict__ bias, void* __restrict__ Cv,
    int Nout, int ldc) {
    constexpr int NT = K / 32;
    __shared__ u16 As[3][4096];
    __shared__ u16 Bs[3][4096];
    const int w = xcd_swz(blockIdx.x, gridDim.x);
    const int bxi = w & ((1 << NXSH) - 1);
    const int byi = w >> NXSH;
    const int tid = threadIdx.x;
    const int wave = tid >> 6, lane = tid & 63;
    const int wr = wave >> 1, wc = wave & 1;
    const size_t brow = (size_t)byi * 128;
    const size_t bcol = (size_t)bxi * 128;
    const int srow = tid >> 2;
    const int qsrc = (tid & 3) ^ ((srow >> 1) & 3);
    const u16* aSrc = A + (brow + srow) * (size_t)K + qsrc * 8;
    const u16* bSrc = Bt + (bcol + srow) * (size_t)K + qsrc * 8;
    const size_t stepRows = (size_t)64 * K;

    auto stage = [&](int t, int buf) {
        const int k0 = t * 32;
        gload_lds16(aSrc + k0, &As[buf][tid * 8]);
        gload_lds16(aSrc + stepRows + k0, &As[buf][tid * 8 + 2048]);
        gload_lds16(bSrc + k0, &Bs[buf][tid * 8]);
        gload_lds16(bSrc + stepRows + k0, &Bs[buf][tid * 8 + 2048]);
    };

    f32x4 acc[4][4] = {};

    stage(0, 0);
    stage(1, 1);
#pragma unroll
    for (int t = 0; t < NT; ++t) {
        const int cur = t % 3;
        if (t + 1 < NT) asm volatile("s_waitcnt vmcnt(4)" ::: "memory");
        else            asm volatile("s_waitcnt vmcnt(0)" ::: "memory");
        __builtin_amdgcn_s_barrier();
        if (t + 2 < NT) stage(t + 2, (t + 2) % 3);
        bf16x8 af[4], bfv[4];
#pragma unroll
        for (int m = 0; m < 4; ++m) {
            const int row = wr * 64 + m * 16 + (lane & 15);
            const int slot = (lane >> 4) ^ ((row >> 1) & 3);
            af[m] = *(const bf16x8*)&As[cur][row * 32 + slot * 8];
        }
#pragma unroll
        for (int n = 0; n < 4; ++n) {
            const int row = wc * 64 + n * 16 + (lane & 15);
            const int slot = (lane >> 4) ^ ((row >> 1) & 3);
            bfv[n] = *(const bf16x8*)&Bs[cur][row * 32 + slot * 8];
        }
#pragma unroll
        for (int m = 0; m < 4; ++m)
#pragma unroll
            for (int n = 0; n < 4; ++n)
                acc[m][n] = __builtin_amdgcn_mfma_f32_16x16x32_bf16(af[m], bfv[n], acc[m][n], 0, 0, 0);
    }

    const int rowSub = wr * 64 + (lane >> 4) * 4;
#pragma unroll
    for (int n = 0; n < 4; ++n) {
        const int col = (int)bcol + wc * 64 + n * 16 + (lane & 15);
        if (col >= Nout) continue;
        const float bv = bias ? bias[col] : 0.0f;
#pragma unroll
        for (int m = 0; m < 4; ++m) {
#pragma unroll
            for (int i = 0; i < 4; ++i) {
                float v = acc[m][n][i] + bv;
                if (RELU) v = fmaxf(v, 0.0f);
                size_t off = (brow + rowSub + m * 16 + i) * (size_t)ldc + col;
                if (OUT_BF16) ((u16*)Cv)[off] = f2bf(v);
                else ((float*)Cv)[off] = v;
            }
        }
    }
}

// ---------------- U0 GEMM with fused concat staging (counted-vmcnt pipeline) -------
// virtual A[row][640] = [nodes_bf(256) | aggr(256) | glob_bf[row>>8](128)]

__global__ __launch_bounds__(256) void gemm_u0_kernel(
    const u16* __restrict__ nodes_bf, const u16* __restrict__ aggr,
    const u16* __restrict__ glob_bf, const u16* __restrict__ U0T,
    const float* __restrict__ bias, u16* __restrict__ C) {
    constexpr int NT = 20;
    __shared__ u16 As[3][4096];
    __shared__ u16 Bs[3][4096];
    const int w = xcd_swz(blockIdx.x, gridDim.x);
    const int bxi = w & 3;
    const int byi = w >> 2;
    const int tid = threadIdx.x;
    const int wave = tid >> 6, lane = tid & 63;
    const int wr = wave >> 1, wc = wave & 1;
    const size_t brow = (size_t)byi * 128;
    const size_t bcol = (size_t)bxi * 128;
    const int srow = tid >> 2;
    const int scol = ((tid & 3) ^ ((srow >> 1) & 3)) * 8;   // swizzled source col
    const int r0i = (int)brow + srow;
    const u16* bSrc = U0T + (bcol + srow) * (size_t)640 + scol;

    auto stage = [&](int t, int buf) {
        const int k0 = t * 32;
        const u16 *p0, *p1;
        if (k0 < 256) {
            p0 = nodes_bf + (size_t)r0i * 256 + k0 + scol;
            p1 = nodes_bf + (size_t)(r0i + 64) * 256 + k0 + scol;
        } else if (k0 < 512) {
            p0 = aggr + (size_t)r0i * 256 + (k0 - 256) + scol;
            p1 = aggr + (size_t)(r0i + 64) * 256 + (k0 - 256) + scol;
        } else {
            p0 = glob_bf + (size_t)(r0i >> 8) * 128 + (k0 - 512) + scol;
            p1 = glob_bf + (size_t)((r0i + 64) >> 8) * 128 + (k0 - 512) + scol;
        }
        gload_lds16(p0, &As[buf][tid * 8]);
        gload_lds16(p1, &As[buf][tid * 8 + 2048]);
        gload_lds16(bSrc + k0, &Bs[buf][tid * 8]);
        gload_lds16(bSrc + (size_t)64 * 640 + k0, &Bs[buf][tid * 8 + 2048]);
    };

    f32x4 acc[4][4] = {};

    stage(0, 0);
    stage(1, 1);
#pragma unroll
    for (int t = 0; t < NT; ++t) {
        const int cur = t % 3;
        if (t + 1 < NT) asm volatile("s_waitcnt vmcnt(4)" ::: "memory");
        else            asm volatile("s_waitcnt vmcnt(0)" ::: "memory");
        __builtin_amdgcn_s_barrier();
        if (t + 2 < NT) stage(t + 2, (t + 2) % 3);
        bf16x8 af[4], bfv[4];
#pragma unroll
        for (int m = 0; m < 4; ++m) {
            const int row = wr * 64 + m * 16 + (lane & 15);
            const int slot = (lane >> 4) ^ ((row >> 1) & 3);
            af[m] = *(const bf16x8*)&As[cur][row * 32 + slot * 8];
        }
#pragma unroll
        for (int n = 0; n < 4; ++n) {
            const int row = wc * 64 + n * 16 + (lane & 15);
            const int slot = (lane >> 4) ^ ((row >> 1) & 3);
            bfv[n] = *(const bf16x8*)&Bs[cur][row * 32 + slot * 8];
        }
#pragma unroll
        for (int m = 0; m < 4; ++m)
#pragma unroll
            for (int n = 0; n < 4; ++n)
                acc[m][n] = __builtin_amdgcn_mfma_f32_16x16x32_bf16(af[m], bfv[n], acc[m][n], 0, 0, 0);
    }

    const int rowSub = wr * 64 + (lane >> 4) * 4;
#pragma unroll
    for (int n = 0; n < 4; ++n) {
        const int col = (int)bcol + wc * 64 + n * 16 + (lane & 15);
        const float bv = bias[col];
#pragma unroll
        for (int m = 0; m < 4; ++m)
#pragma unroll
            for (int i = 0; i < 4; ++i) {
                float v = fmaxf(acc[m][n][i] + bv, 0.0f);
                C[(brow + rowSub + m * 16 + i) * (size_t)512 + col] = f2bf(v);
            }
    }
}

// ---------------- Gdb = global_attr @ msg_w0[576:704] + b0; also glob_bf ----------

__global__ __launch_bounds__(256) void gd_kernel(const float* __restrict__ glob,
                                                 const float* __restrict__ msg_w0,
                                                 const float* __restrict__ b0,
                                                 float* __restrict__ Gdb,
                                                 u16* __restrict__ glob_bf) {
    int g = blockIdx.x;
    __shared__ float in[TFG];
    if (threadIdx.x < TFG) {
        float v = glob[g * TFG + threadIdx.x];
        in[threadIdx.x] = v;
        glob_bf[g * TFG + threadIdx.x] = f2bf(v);
    }
    __syncthreads();
    for (int j = threadIdx.x; j < 512; j += 256) {
        float s = b0[j];
        for (int k = 0; k < TFG; ++k) s += in[k] * msg_w0[(size_t)(576 + k) * 512 + j];
        Gdb[(size_t)g * 512 + j] = s;
    }
}

// ---------------- fused layer-1: h1 = relu(Ef@Wb + Pac[s] + Pac[t,512+] + Gdb) ----
// [128][64] tiles, 8 slots/row, swizzle slot ^= (row&7) (16-way -> 2-way conflicts)

__global__ __launch_bounds__(256) void h1_fused_kernel(
    const float* __restrict__ Ef, const u16* __restrict__ WbT,
    const u16* __restrict__ Pac, const float* __restrict__ Gdb,
    const int* __restrict__ src, const int* __restrict__ tgt,
    u16* __restrict__ h1, int e0) {
    __shared__ u16 smem[17408];          // As[0..8192) | Bs[8192..16384); Eb overlays (stride 136)
    u16* As = smem;
    u16* Bs = smem + 8192;
    const int w = xcd_swz(blockIdx.x, gridDim.x);
    const int bxi = w & 3;
    const int byi = w >> 2;
    const int tid = threadIdx.x;
    const int wave = tid >> 6, lane = tid & 63;
    const int wr = wave >> 1, wc = wave & 1;
    const int brow = byi * 128;
    const int bcol = bxi * 128;

    // phase 1a: stage edge tile (f32 -> bf16, swizzled dest slots) + Wb (gload,
    // swizzled source slot)
    {
        const int r = tid >> 2;
        const int cq = (tid & 3) * 2;    // global slots cq, cq+1 (8 u16 each)
        const int sw = r & 7;
#pragma unroll
        for (int h = 0; h < 2; ++h) {
            const float* sp = Ef + (size_t)(e0 + brow + r + h * 64) * 64 + cq * 8;
            f32x4 v0 = *(const f32x4*)(sp);
            f32x4 v1 = *(const f32x4*)(sp + 4);
            f32x4 v2 = *(const f32x4*)(sp + 8);
            f32x4 v3 = *(const f32x4*)(sp + 12);
            u16x8 o0, o1;
            o0[0] = f2bf(v0.x); o0[1] = f2bf(v0.y); o0[2] = f2bf(v0.z); o0[3] = f2bf(v0.w);
            o0[4] = f2bf(v1.x); o0[5] = f2bf(v1.y); o0[6] = f2bf(v1.z); o0[7] = f2bf(v1.w);
            o1[0] = f2bf(v2.x); o1[1] = f2bf(v2.y); o1[2] = f2bf(v2.z); o1[3] = f2bf(v2.w);
            o1[4] = f2bf(v3.x); o1[5] = f2bf(v3.y); o1[6] = f2bf(v3.z); o1[7] = f2bf(v3.w);
            *(u16x8*)&As[(r + h * 64) * 64 + (cq ^ sw) * 8] = o0;
            *(u16x8*)&As[(r + h * 64) * 64 + ((cq + 1) ^ sw) * 8] = o1;
        }
#pragma unroll
        for (int j = 0; j < 4; ++j) {
            int li = j * 256 + tid;      // dest slot li&7, row li>>3
            int row = li >> 3;
            int gslot = (li & 7) ^ (row & 7);
            gload_lds16(WbT + (size_t)(bcol + row) * 64 + gslot * 8, &Bs[li * 8]);
        }
    }
    __syncthreads();

    // phase 1b: MFMA  (Eb tile = edges x Wb^T, K = 64)
    f32x4 acc[4][4] = {};
#pragma unroll
    for (int k0 = 0; k0 < 64; k0 += 32) {
        bf16x8 af[4], bv[4];
#pragma unroll
        for (int m = 0; m < 4; ++m) {
            const int row = wr * 64 + m * 16 + (lane & 15);
            const int slot = ((k0 >> 3) + (lane >> 4)) ^ (row & 7);
            af[m] = *(const bf16x8*)&As[row * 64 + slot * 8];
        }
#pragma unroll
        for (int n = 0; n < 4; ++n) {
            const int row = wc * 64 + n * 16 + (lane & 15);
            const int slot = ((k0 >> 3) + (lane >> 4)) ^ (row & 7);
            bv[n] = *(const bf16x8*)&Bs[row * 64 + slot * 8];
        }
#pragma unroll
        for (int m = 0; m < 4; ++m)
#pragma unroll
            for (int n = 0; n < 4; ++n)
                acc[m][n] = __builtin_amdgcn_mfma_f32_16x16x32_bf16(af[m], bv[n], acc[m][n], 0, 0, 0);
    }
    __syncthreads();

    // phase 2: acc -> Eb LDS (bf16, stride 136)
    const int rowSub = wr * 64 + (lane >> 4) * 4;
#pragma unroll
    for (int m = 0; m < 4; ++m)
#pragma unroll
        for (int n = 0; n < 4; ++n)
#pragma unroll
            for (int i = 0; i < 4; ++i)
                smem[(rowSub + m * 16 + i) * 136 + wc * 64 + n * 16 + (lane & 15)] =
                    f2bf(acc[m][n][i]);
    __syncthreads();

    // phase 3: gather-add, row-coalesced (16 lanes = one edge row's 128 cols)
#pragma unroll
    for (int it = 0; it < 8; ++it) {
        int lin = it * 256 + tid;        // 0..2047
        int r = lin >> 4;                // 0..127
        int q = (lin & 15) * 8;          // 0..120
        int e = e0 + brow + r;
        int s = src[e];
        int t = tgt[e];
        int g = e >> 11;
        int col = bcol + q;
        u16x8 pa = *(const u16x8*)(Pac + (size_t)s * 1024 + col);
        u16x8 pc = *(const u16x8*)(Pac + (size_t)t * 1024 + 512 + col);
        u16x8 eb = *(const u16x8*)&smem[r * 136 + q];
        f32x4 g0 = *(const f32x4*)(Gdb + (size_t)g * 512 + col);
        f32x4 g1 = *(const f32x4*)(Gdb + (size_t)g * 512 + col + 4);
        u16x8 o;
#pragma unroll
        for (int j = 0; j < 8; ++j) {
            float gd = (j < 4) ? g0[j] : g1[j - 4];
            float v = b2f(pa[j]) + b2f(pc[j]) + b2f(eb[j]) + gd;
            o[j] = f2bf(fmaxf(v, 0.0f));
        }
        *(u16x8*)(h1 + (size_t)(brow + r) * 512 + col) = o;
    }
}

// ---------------- scatter-max: aggr[n,f] = max over edges with tgt==n --------------
// block = (graph, 64-feat chunk); 64 edge-lanes x 16 feat-groups; u16x4 loads.

__global__ __launch_bounds__(1024) void scatter_max_kernel(
    const u16* __restrict__ msg, const int* __restrict__ tgt,
    u16* __restrict__ aggr, int g0, int e0) {
    int g = g0 + (blockIdx.x >> 2);
    int fc = blockIdx.x & 3;
    __shared__ unsigned smax[256 * 64];  // 64 KiB
    int tid = threadIdx.x;
    for (int i = tid; i < 256 * 64; i += 1024) smax[i] = 0u;
    __syncthreads();
    const int eg = g * 2048;
    const int n0 = g * 256;
    const int f4 = (tid & 15) * 4;       // feat offset 0..60
    const int elane = tid >> 4;          // 0..63
    const u16* mbase = msg + fc * 64 + f4;
#pragma unroll
    for (int wv = 0; wv < 32; wv += 4) {
        const int e = eg + elane + wv * 64;
        int t0 = tgt[e], t1 = tgt[e + 64], t2 = tgt[e + 128], t3 = tgt[e + 192];
        u16x4 m0 = *(const u16x4*)(mbase + (size_t)(e       - e0) * 256);
        u16x4 m1 = *(const u16x4*)(mbase + (size_t)(e +  64 - e0) * 256);
        u16x4 m2 = *(const u16x4*)(mbase + (size_t)(e + 128 - e0) * 256);
        u16x4 m3 = *(const u16x4*)(mbase + (size_t)(e + 192 - e0) * 256);
        int a0 = t0 - n0, a1 = t1 - n0, a2 = t2 - n0, a3 = t3 - n0;
        if ((unsigned)a0 < 256u) {
            atomicMax(&smax[a0 * 64 + f4],     ((unsigned)m0.x) << 16);
            atomicMax(&smax[a0 * 64 + f4 + 1], ((unsigned)m0.y) << 16);
            atomicMax(&smax[a0 * 64 + f4 + 2], ((unsigned)m0.z) << 16);
            atomicMax(&smax[a0 * 64 + f4 + 3], ((unsigned)m0.w) << 16);
        }
        if ((unsigned)a1 < 256u) {
            atomicMax(&smax[a1 * 64 + f4],     ((unsigned)m1.x) << 16);
            atomicMax(&smax[a1 * 64 + f4 + 1], ((unsigned)m1.y) << 16);
            atomicMax(&smax[a1 * 64 + f4 + 2], ((unsigned)m1.z) << 16);
            atomicMax(&smax[a1 * 64 + f4 + 3], ((unsigned)m1.w) << 16);
        }
        if ((unsigned)a2 < 256u) {
            atomicMax(&smax[a2 * 64 + f4],     ((unsigned)m2.x) << 16);
            atomicMax(&smax[a2 * 64 + f4 + 1], ((unsigned)m2.y) << 16);
            atomicMax(&smax[a2 * 64 + f4 + 2], ((unsigned)m2.z) << 16);
            atomicMax(&smax[a2 * 64 + f4 + 3], ((unsigned)m2.w) << 16);
        }
        if ((unsigned)a3 < 256u) {
            atomicMax(&smax[a3 * 64 + f4],     ((unsigned)m3.x) << 16);
            atomicMax(&smax[a3 * 64 + f4 + 1], ((unsigned)m3.y) << 16);
            atomicMax(&smax[a3 * 64 + f4 + 2], ((unsigned)m3.z) << 16);
            atomicMax(&smax[a3 * 64 + f4 + 3], ((unsigned)m3.w) << 16);
        }
    }
    __syncthreads();
    for (int i = tid; i < 256 * 64; i += 1024) {
        int nl = i >> 6, ff = i & 63;
        aggr[(size_t)(n0 + nl) * 256 + fc * 64 + ff] = (u16)(smax[nl * 64 + ff] >> 16);
    }
}

// ---------------- merged head: agg_nodes + glob matvec + action softmax ------------

__global__ __launch_bounds__(256) void head_kernel(
    const u16* __restrict__ h, const float* __restrict__ glob,
    const float* __restrict__ W, const float* __restrict__ b,
    const float* __restrict__ actw, const float* __restrict__ actb,
    float* __restrict__ out_act) {
    int g = blockIdx.x;
    int tid = threadIdx.x;
    __shared__ float in[384];
    __shared__ float go[256];
    __shared__ float logits[8];
    // phase A: per-feature max over the graph's 256 nodes
    {
        const size_t base = (size_t)g * 256 * 256 + tid;
        float m0 = 0.0f, m1 = 0.0f, m2 = 0.0f, m3 = 0.0f;
        for (int n = 0; n < 256; n += 4) {
            m0 = fmaxf(m0, b2f(h[base + (size_t)n * 256]));
            m1 = fmaxf(m1, b2f(h[base + (size_t)(n + 1) * 256]));
            m2 = fmaxf(m2, b2f(h[base + (size_t)(n + 2) * 256]));
            m3 = fmaxf(m3, b2f(h[base + (size_t)(n + 3) * 256]));
        }
        in[tid] = fmaxf(fmaxf(m0, m1), fmaxf(m2, m3));
        if (tid < 128) in[256 + tid] = glob[(size_t)g * 128 + tid];
    }
    __syncthreads();
    // phase B: gout = relu([agg | glob] @ W + b)
    {
        float s = b[tid];
        for (int k = 0; k < 384; ++k) s += in[k] * W[(size_t)k * 256 + tid];
        go[tid] = fmaxf(s, 0.0f);
    }
    __syncthreads();
    // phase C: action = softmax(go @ actw + actb)
    if (tid < 8) {
        float s = actb[tid];
        for (int k = 0; k < 256; ++k) s += go[k] * actw[(size_t)k * 8 + tid];
        logits[tid] = s;
    }
    __syncthreads();
    if (tid == 0) {
        float mx = logits[0];
        for (int i = 1; i < 8; ++i) mx = fmaxf(mx, logits[i]);
        float ex[8], den = 0.0f;
        for (int i = 0; i < 8; ++i) { ex[i] = expf(logits[i] - mx); den += ex[i]; }
        float inv = 1.0f / den;
        for (int i = 0; i < 8; ++i) out_act[(size_t)g * 8 + i] = ex[i] * inv;
    }
}

// ---------------- workspace layout ----------------

constexpr size_t OFF_NODES_BF = 0;                                    // 8388608
constexpr size_t OFF_GLOB_BF  = OFF_NODES_BF + (size_t)TNN * TFN * 2; // 16384
constexpr size_t OFF_WACT = OFF_GLOB_BF + (size_t)TNG * TFG * 2;      // 1024*256*2
constexpr size_t OFF_WBT  = OFF_WACT + 1024 * 256 * 2;                // 512*64*2
constexpr size_t OFF_W1T  = OFF_WBT + 512 * 64 * 2;                   // 512*512*2
constexpr size_t OFF_W2T  = OFF_W1T + 512 * 512 * 2;                  // 256*512*2
constexpr size_t OFF_U0T  = OFF_W2T + 256 * 512 * 2;                  // 512*640*2
constexpr size_t OFF_U1T  = OFF_U0T + 512 * 640 * 2;                  // 256*512*2
constexpr size_t OFF_EMBT = OFF_U1T + 256 * 512 * 2;                  // 128*256*2
constexpr size_t OFF_AGGR = OFF_EMBT + 128 * 256 * 2;                 // 16384*256*2
constexpr size_t OFF_GDB  = OFF_AGGR + (size_t)TNN * 256 * 2;         // 64*512*4
constexpr size_t OFF_PAC  = OFF_GDB + 64 * 512 * 4;                   // 16384*1024*2
constexpr size_t OFF_V    = OFF_PAC + (size_t)TNN * 1024 * 2;         // ~53 MB
constexpr size_t SZ_HU1   = (size_t)TNN * 512 * 2;

extern "C" void kernel_launch(void* const* d_in, const int* in_sizes, int n_in,
                              void* d_out, int out_size, void* d_ws, size_t ws_size,
                              hipStream_t stream) {
    const float* nodes       = (const float*)d_in[0];
    const float* edge_attr   = (const float*)d_in[1];
    const float* global_attr = (const float*)d_in[2];
    const int*   edge_idx    = (const int*)d_in[3];
    const float* msg_w0 = (const float*)d_in[7];
    const float* msg_b0 = (const float*)d_in[8];
    const float* msg_w1 = (const float*)d_in[9];
    const float* msg_b1 = (const float*)d_in[10];
    const float* msg_w2 = (const float*)d_in[11];
    const float* msg_b2 = (const float*)d_in[12];
    const float* upd_w0 = (const float*)d_in[13];
    const float* upd_b0 = (const float*)d_in[14];
    const float* upd_w1 = (const float*)d_in[15];
    const float* upd_b1 = (const float*)d_in[16];
    const float* glob_w = (const float*)d_in[17];
    const float* glob_b = (const float*)d_in[18];
    const float* emb_w  = (const float*)d_in[19];
    const float* emb_b  = (const float*)d_in[20];
    const float* act_w  = (const float*)d_in[21];
    const float* act_b  = (const float*)d_in[22];

    const int* src = edge_idx;
    const int* tgt = edge_idx + TNE;

    char* ws = (char*)d_ws;
    u16* nodes_bf = (u16*)(ws + OFF_NODES_BF);
    u16* glob_bf  = (u16*)(ws + OFF_GLOB_BF);
    u16* WacT = (u16*)(ws + OFF_WACT);
    u16* WbT  = (u16*)(ws + OFF_WBT);
    u16* W1T  = (u16*)(ws + OFF_W1T);
    u16* W2T  = (u16*)(ws + OFF_W2T);
    u16* U0T  = (u16*)(ws + OFF_U0T);
    u16* U1T  = (u16*)(ws + OFF_U1T);
    u16* EmbT = (u16*)(ws + OFF_EMBT);
    u16* aggr = (u16*)(ws + OFF_AGGR);
    float* Gdb = (float*)(ws + OFF_GDB);
    u16* Pac  = (u16*)(ws + OFF_PAC);
    float* out = (float*)d_out;

    // chunk size: largest power-of-two CH (multiple of 2048) fitting ws
    size_t CH = (size_t)TNE;
    while (CH > 2048) {
        size_t need = OFF_V + (CH * 2560 > SZ_HU1 ? CH * 2560 : SZ_HU1);
        if (need <= ws_size) break;
        CH >>= 1;
    }
    const int nchunk = (int)((size_t)TNE / CH);
    const int gpc = (int)(CH / 2048);

    u16* h1c  = (u16*)(ws + OFF_V);
    u16* h2c  = (u16*)(ws + OFF_V + CH * 1024);
    u16* msgc = (u16*)(ws + OFF_V + CH * 2048);
    u16* hu1  = (u16*)(ws + OFF_V);            // node phase (edge buffers dead)
    u16* h_bf = (u16*)(ws + OFF_AGGR);         // overlays aggr (dead after U0)

    // ---- setup ----
    cast_kernel<<<(TNN * TFN / 4 + 255) / 256, 256, 0, stream>>>(nodes, nodes_bf, TNN * TFN / 4);

    PrepTab tab;
    int ntiles = 0;
    {
        const float* Ws[8]  = {msg_w0, msg_w0, msg_w0, msg_w1, msg_w2, upd_w0, upd_w1, emb_w};
        int offs[8] = {(int)(OFF_WACT / 2), (int)(OFF_WACT / 2) + 131072, (int)(OFF_WBT / 2),
                       (int)(OFF_W1T / 2), (int)(OFF_W2T / 2), (int)(OFF_U0T / 2),
                       (int)(OFF_U1T / 2), (int)(OFF_EMBT / 2)};
        int nin[8]  = {512, 512, 512, 512, 256, 512, 256, 64};
        int nact[8] = {512, 512, 512, 512, 256, 512, 256, 64};
        int r0v[8]  = {0, 320, 256, 0, 0, 0, 0, 0};
        int ksub[8] = {256, 256, 64, 512, 512, 640, 512, 256};
        int npad[8] = {512, 512, 512, 512, 256, 512, 256, 128};
        int acc = 0;
        for (int i = 0; i < 8; ++i) {
            tab.W[i] = Ws[i]; tab.out_off[i] = offs[i]; tab.Nin[i] = nin[i];
            tab.Nact[i] = nact[i]; tab.r0[i] = r0v[i]; tab.Ksub[i] = ksub[i];
            tab.tkn[i] = ksub[i] / 64;
            tab.tile0[i] = acc;
            acc += (npad[i] / 64) * (ksub[i] / 64);
        }
        ntiles = acc;   // 288
    }
    prep_weights_kernel<<<ntiles, 256, 0, stream>>>(tab, (u16*)ws);
    gd_kernel<<<64, 256, 0, stream>>>(global_attr, msg_w0, msg_b0, Gdb, glob_bf);

    // Pac = nodes_bf @ [Wa | Wc]^T   (M=16384, N=1024, K=256) -- 256x256 tiles
    gemm_bt256_kernel<256, 2, false, true><<<256, 512, 0, stream>>>(nodes_bf, WacT, nullptr, Pac, 1024, 1024);

    // ---- edge pipeline (chunked) ----
    for (int ci = 0; ci < nchunk; ++ci) {
        const int e0 = (int)(ci * CH);
        const int nwg128 = (int)(CH / 32);   // 4 * CH/128 (h1_fused)
        const int mb256 = (int)(CH / 256);
        h1_fused_kernel<<<nwg128, 256, 0, stream>>>(
            edge_attr, WbT, Pac, Gdb, src, tgt, h1c, e0);
        gemm_bt256_kernel<512, 1, true, true><<<mb256 * 2, 512, 0, stream>>>(h1c, W1T, msg_b1, h2c, 512, 512);
        gemm_bt256_kernel<512, 0, true, true><<<mb256, 512, 0, stream>>>(h2c, W2T, msg_b2, msgc, 256, 256);
        scatter_max_kernel<<<gpc * 4, 1024, 0, stream>>>(msgc, tgt, aggr, ci * gpc, e0);
    }

    // ---- node update MLP (concat fused into U0 staging) ----
    gemm_u0_kernel<<<512, 256, 0, stream>>>(nodes_bf, aggr, glob_bf, U0T, upd_b0, hu1);
    gemm_bt256_kernel<512, 0, true, true><<<64, 512, 0, stream>>>(hu1, U1T, upd_b1, h_bf, 256, 256);

    // ---- heads ----
    head_kernel<<<64, 256, 0, stream>>>(h_bf, global_attr, glob_w, glob_b,
                                        act_w, act_b, out + (size_t)TNN * 64);
    gemm_bt_kernel<256, 0, true, false><<<128, 256, 0, stream>>>(h_bf, EmbT, emb_b, out, 64, 64);

    (void)in_sizes; (void)n_in; (void)out_size;
}

// Round 9
// 348.736 us; speedup vs baseline: 1.0883x; 1.0883x over previous
//
#include <hip/hip_runtime.h>
#include <hip/hip_bf16.h>

typedef unsigned short u16;
using u16x4 = __attribute__((ext_vector_type(4))) unsigned short;
using u16x8 = __attribute__((ext_vector_type(8))) unsigned short;
using u32x4 = __attribute__((ext_vector_type(4))) unsigned int;
using f32x4 = __attribute__((ext_vector_type(4))) float;
using bf16x8 = __attribute__((ext_vector_type(8))) __bf16;

#define TNG 64
#define TNN 16384
#define TNE 131072
#define TFN 256
#define TFE 64
#define TFG 128
// graphs are fixed-size: edge e -> graph e>>11, node n -> graph n>>8

__device__ __forceinline__ u16 f2bf(float f) {
    unsigned u = __float_as_uint(f);
    unsigned r = (u + 0x7FFFu + ((u >> 16) & 1u)) >> 16;
    return (u16)r;
}
__device__ __forceinline__ float b2f(u16 h) {
    return __uint_as_float(((unsigned)h) << 16);
}

// async global->LDS, 16B per lane (dest must be linear: base + lane*16)
__device__ __forceinline__ void gload_lds16(const u16* g, u16* l) {
    __builtin_amdgcn_global_load_lds(
        (const __attribute__((address_space(1))) void*)g,
        (__attribute__((address_space(3))) void*)l, 16, 0, 0);
}

// chunked XCD swizzle: nwg % 8 == 0 -> XCD k gets a contiguous work range
__device__ __forceinline__ int xcd_swz(int bid, int nwg) {
    return (nwg & 7) == 0 ? (bid & 7) * (nwg >> 3) + (bid >> 3) : bid;
}

// ---------------- setup: f32 -> bf16 cast ----------------

__global__ void cast_kernel(const float* __restrict__ in, u16* __restrict__ out, int n4) {
    int i = blockIdx.x * 256 + threadIdx.x;
    if (i >= n4) return;
    f32x4 v = *(const f32x4*)(in + (size_t)i * 4);
    u16x4 o;
    o.x = f2bf(v.x); o.y = f2bf(v.y); o.z = f2bf(v.z); o.w = f2bf(v.w);
    *(u16x4*)(out + (size_t)i * 4) = o;
}

// ---------------- weight transpose+cast via LDS 64x64 tiles (coalesced both sides) --
// out[n*Ksub + k] = (n < Nact) ? W[(r0+k)*Nin + n] : 0

struct PrepTab {
    const float* W[8];
    int out_off[8];   // u16 offset from ws base
    int Nin[8], Nact[8], r0[8], Ksub[8];
    int tile0[8];     // prefix sum of tile counts; tiles = (Npad/64)*(Ksub/64)
    int tkn[8];       // Ksub/64
};

__global__ __launch_bounds__(256) void prep_weights_kernel(PrepTab tab, u16* __restrict__ wsbase) {
    const int b = blockIdx.x;
    int i = 7;
#pragma unroll
    for (int j = 7; j > 0; --j)
        if (b < tab.tile0[j]) i = j - 1;
    const int loc = b - tab.tile0[i];
    const int tk = loc % tab.tkn[i];
    const int tn = loc / tab.tkn[i];
    const int kb = tk * 64, nb = tn * 64;
    const int Nin = tab.Nin[i], Nact = tab.Nact[i], r0 = tab.r0[i], Ksub = tab.Ksub[i];
    const float* W = tab.W[i];
    u16* outp = wsbase + tab.out_off[i];

    __shared__ float t[64][65];
    const int tid = threadIdx.x;
    const int nl = tid & 63;
    const bool nok = (nb + nl) < Nact;
#pragma unroll 4
    for (int kk = tid >> 6; kk < 64; kk += 4) {
        float v = nok ? W[(size_t)(r0 + kb + kk) * Nin + nb + nl] : 0.0f;
        t[kk][nl] = v;
    }
    __syncthreads();
    const int kl = tid & 63;
#pragma unroll 4
    for (int nn = tid >> 6; nn < 64; nn += 4)
        outp[(size_t)(nb + nn) * Ksub + kb + kl] = f2bf(t[kl][nn]);
}

// ---------------- bf16 MFMA GEMM: C = act(A[M,K] @ Bt[N,K]^T + bias) ----------------
// Counted-vmcnt pipeline (T4): 3 LDS buffers, prefetch depth 2, ONE raw s_barrier per
// K-step, s_waitcnt vmcnt(4) in-loop (never 0 until the tail).
// Bank swizzle: LDS(row, s) holds global slot s ^ ((row>>1)&3)  [both sides, rule #21]

template <int K, int NXSH, bool RELU, bool OUT_BF16>
__global__ __launch_bounds__(256) void gemm_bt_kernel(
    const u16* __restrict__ A, const u16* __restrict__ Bt,
    const float* __restrict__ bias, void* __restrict__ Cv,
    int Nout, int ldc) {
    constexpr int NT = K / 32;
    __shared__ u16 As[3][4096];
    __shared__ u16 Bs[3][4096];
    const int w = xcd_swz(blockIdx.x, gridDim.x);
    const int bxi = w & ((1 << NXSH) - 1);
    const int byi = w >> NXSH;
    const int tid = threadIdx.x;
    const int wave = tid >> 6, lane = tid & 63;
    const int wr = wave >> 1, wc = wave & 1;
    const size_t brow = (size_t)byi * 128;
    const size_t bcol = (size_t)bxi * 128;
    const int srow = tid >> 2;
    const int qsrc = (tid & 3) ^ ((srow >> 1) & 3);   // swizzled source slot
    const u16* aSrc = A + (brow + srow) * (size_t)K + qsrc * 8;
    const u16* bSrc = Bt + (bcol + srow) * (size_t)K + qsrc * 8;
    const size_t stepRows = (size_t)64 * K;

    auto stage = [&](int t, int buf) {
        const int k0 = t * 32;
        gload_lds16(aSrc + k0, &As[buf][tid * 8]);
        gload_lds16(aSrc + stepRows + k0, &As[buf][tid * 8 + 2048]);
        gload_lds16(bSrc + k0, &Bs[buf][tid * 8]);
        gload_lds16(bSrc + stepRows + k0, &Bs[buf][tid * 8 + 2048]);
    };

    f32x4 acc[4][4] = {};

    stage(0, 0);
    stage(1, 1);
#pragma unroll
    for (int t = 0; t < NT; ++t) {
        const int cur = t % 3;
        if (t + 1 < NT) asm volatile("s_waitcnt vmcnt(4)" ::: "memory");
        else            asm volatile("s_waitcnt vmcnt(0)" ::: "memory");
        __builtin_amdgcn_s_barrier();
        if (t + 2 < NT) stage(t + 2, (t + 2) % 3);
        bf16x8 af[4], bfv[4];
#pragma unroll
        for (int m = 0; m < 4; ++m) {
            const int row = wr * 64 + m * 16 + (lane & 15);
            const int slot = (lane >> 4) ^ ((row >> 1) & 3);
            af[m] = *(const bf16x8*)&As[cur][row * 32 + slot * 8];
        }
#pragma unroll
        for (int n = 0; n < 4; ++n) {
            const int row = wc * 64 + n * 16 + (lane & 15);
            const int slot = (lane >> 4) ^ ((row >> 1) & 3);
            bfv[n] = *(const bf16x8*)&Bs[cur][row * 32 + slot * 8];
        }
#pragma unroll
        for (int m = 0; m < 4; ++m)
#pragma unroll
            for (int n = 0; n < 4; ++n)
                acc[m][n] = __builtin_amdgcn_mfma_f32_16x16x32_bf16(af[m], bfv[n], acc[m][n], 0, 0, 0);
    }

    const int rowSub = wr * 64 + (lane >> 4) * 4;
#pragma unroll
    for (int n = 0; n < 4; ++n) {
        const int col = (int)bcol + wc * 64 + n * 16 + (lane & 15);
        if (col >= Nout) continue;
        const float bv = bias ? bias[col] : 0.0f;
#pragma unroll
        for (int m = 0; m < 4; ++m) {
#pragma unroll
            for (int i = 0; i < 4; ++i) {
                float v = acc[m][n][i] + bv;
                if (RELU) v = fmaxf(v, 0.0f);
                size_t off = (brow + rowSub + m * 16 + i) * (size_t)ldc + col;
                if (OUT_BF16) ((u16*)Cv)[off] = f2bf(v);
                else ((float*)Cv)[off] = v;
            }
        }
    }
}

// ---------------- U0 GEMM with fused concat staging (counted-vmcnt pipeline) -------
// virtual A[row][640] = [nodes_bf(256) | aggr(256) | glob_bf[row>>8](128)]

__global__ __launch_bounds__(256) void gemm_u0_kernel(
    const u16* __restrict__ nodes_bf, const u16* __restrict__ aggr,
    const u16* __restrict__ glob_bf, const u16* __restrict__ U0T,
    const float* __restrict__ bias, u16* __restrict__ C) {
    constexpr int NT = 20;
    __shared__ u16 As[3][4096];
    __shared__ u16 Bs[3][4096];
    const int w = xcd_swz(blockIdx.x, gridDim.x);
    const int bxi = w & 3;
    const int byi = w >> 2;
    const int tid = threadIdx.x;
    const int wave = tid >> 6, lane = tid & 63;
    const int wr = wave >> 1, wc = wave & 1;
    const size_t brow = (size_t)byi * 128;
    const size_t bcol = (size_t)bxi * 128;
    const int srow = tid >> 2;
    const int scol = ((tid & 3) ^ ((srow >> 1) & 3)) * 8;   // swizzled source col
    const int r0i = (int)brow + srow;
    const u16* bSrc = U0T + (bcol + srow) * (size_t)640 + scol;

    auto stage = [&](int t, int buf) {
        const int k0 = t * 32;
        const u16 *p0, *p1;
        if (k0 < 256) {
            p0 = nodes_bf + (size_t)r0i * 256 + k0 + scol;
            p1 = nodes_bf + (size_t)(r0i + 64) * 256 + k0 + scol;
        } else if (k0 < 512) {
            p0 = aggr + (size_t)r0i * 256 + (k0 - 256) + scol;
            p1 = aggr + (size_t)(r0i + 64) * 256 + (k0 - 256) + scol;
        } else {
            p0 = glob_bf + (size_t)(r0i >> 8) * 128 + (k0 - 512) + scol;
            p1 = glob_bf + (size_t)((r0i + 64) >> 8) * 128 + (k0 - 512) + scol;
        }
        gload_lds16(p0, &As[buf][tid * 8]);
        gload_lds16(p1, &As[buf][tid * 8 + 2048]);
        gload_lds16(bSrc + k0, &Bs[buf][tid * 8]);
        gload_lds16(bSrc + (size_t)64 * 640 + k0, &Bs[buf][tid * 8 + 2048]);
    };

    f32x4 acc[4][4] = {};

    stage(0, 0);
    stage(1, 1);
#pragma unroll
    for (int t = 0; t < NT; ++t) {
        const int cur = t % 3;
        if (t + 1 < NT) asm volatile("s_waitcnt vmcnt(4)" ::: "memory");
        else            asm volatile("s_waitcnt vmcnt(0)" ::: "memory");
        __builtin_amdgcn_s_barrier();
        if (t + 2 < NT) stage(t + 2, (t + 2) % 3);
        bf16x8 af[4], bfv[4];
#pragma unroll
        for (int m = 0; m < 4; ++m) {
            const int row = wr * 64 + m * 16 + (lane & 15);
            const int slot = (lane >> 4) ^ ((row >> 1) & 3);
            af[m] = *(const bf16x8*)&As[cur][row * 32 + slot * 8];
        }
#pragma unroll
        for (int n = 0; n < 4; ++n) {
            const int row = wc * 64 + n * 16 + (lane & 15);
            const int slot = (lane >> 4) ^ ((row >> 1) & 3);
            bfv[n] = *(const bf16x8*)&Bs[cur][row * 32 + slot * 8];
        }
#pragma unroll
        for (int m = 0; m < 4; ++m)
#pragma unroll
            for (int n = 0; n < 4; ++n)
                acc[m][n] = __builtin_amdgcn_mfma_f32_16x16x32_bf16(af[m], bfv[n], acc[m][n], 0, 0, 0);
    }

    const int rowSub = wr * 64 + (lane >> 4) * 4;
#pragma unroll
    for (int n = 0; n < 4; ++n) {
        const int col = (int)bcol + wc * 64 + n * 16 + (lane & 15);
        const float bv = bias[col];
#pragma unroll
        for (int m = 0; m < 4; ++m)
#pragma unroll
            for (int i = 0; i < 4; ++i) {
                float v = fmaxf(acc[m][n][i] + bv, 0.0f);
                C[(brow + rowSub + m * 16 + i) * (size_t)512 + col] = f2bf(v);
            }
    }
}

// ---------------- Gdb = global_attr @ msg_w0[576:704] + b0; also glob_bf ----------

__global__ __launch_bounds__(256) void gd_kernel(const float* __restrict__ glob,
                                                 const float* __restrict__ msg_w0,
                                                 const float* __restrict__ b0,
                                                 float* __restrict__ Gdb,
                                                 u16* __restrict__ glob_bf) {
    int g = blockIdx.x;
    __shared__ float in[TFG];
    if (threadIdx.x < TFG) {
        float v = glob[g * TFG + threadIdx.x];
        in[threadIdx.x] = v;
        glob_bf[g * TFG + threadIdx.x] = f2bf(v);
    }
    __syncthreads();
    for (int j = threadIdx.x; j < 512; j += 256) {
        float s = b0[j];
        for (int k = 0; k < TFG; ++k) s += in[k] * msg_w0[(size_t)(576 + k) * 512 + j];
        Gdb[(size_t)g * 512 + j] = s;
    }
}

// ---------------- fused layer-1: h1 = relu(Ef@Wb + Pac[s] + Pac[t,512+] + Gdb) ----
// [128][64] tiles, 8 slots/row, swizzle slot ^= (row&7) (16-way -> 2-way conflicts)

__global__ __launch_bounds__(256) void h1_fused_kernel(
    const float* __restrict__ Ef, const u16* __restrict__ WbT,
    const u16* __restrict__ Pac, const float* __restrict__ Gdb,
    const int* __restrict__ src, const int* __restrict__ tgt,
    u16* __restrict__ h1, int e0) {
    __shared__ u16 smem[17408];          // As[0..8192) | Bs[8192..16384); Eb overlays (stride 136)
    u16* As = smem;
    u16* Bs = smem + 8192;
    const int w = xcd_swz(blockIdx.x, gridDim.x);
    const int bxi = w & 3;
    const int byi = w >> 2;
    const int tid = threadIdx.x;
    const int wave = tid >> 6, lane = tid & 63;
    const int wr = wave >> 1, wc = wave & 1;
    const int brow = byi * 128;
    const int bcol = bxi * 128;

    // phase 1a: stage edge tile (f32 -> bf16, swizzled dest slots) + Wb (gload,
    // swizzled source slot)
    {
        const int r = tid >> 2;
        const int cq = (tid & 3) * 2;    // global slots cq, cq+1 (8 u16 each)
        const int sw = r & 7;
#pragma unroll
        for (int h = 0; h < 2; ++h) {
            const float* sp = Ef + (size_t)(e0 + brow + r + h * 64) * 64 + cq * 8;
            f32x4 v0 = *(const f32x4*)(sp);
            f32x4 v1 = *(const f32x4*)(sp + 4);
            f32x4 v2 = *(const f32x4*)(sp + 8);
            f32x4 v3 = *(const f32x4*)(sp + 12);
            u16x8 o0, o1;
            o0[0] = f2bf(v0.x); o0[1] = f2bf(v0.y); o0[2] = f2bf(v0.z); o0[3] = f2bf(v0.w);
            o0[4] = f2bf(v1.x); o0[5] = f2bf(v1.y); o0[6] = f2bf(v1.z); o0[7] = f2bf(v1.w);
            o1[0] = f2bf(v2.x); o1[1] = f2bf(v2.y); o1[2] = f2bf(v2.z); o1[3] = f2bf(v2.w);
            o1[4] = f2bf(v3.x); o1[5] = f2bf(v3.y); o1[6] = f2bf(v3.z); o1[7] = f2bf(v3.w);
            *(u16x8*)&As[(r + h * 64) * 64 + (cq ^ sw) * 8] = o0;
            *(u16x8*)&As[(r + h * 64) * 64 + ((cq + 1) ^ sw) * 8] = o1;
        }
#pragma unroll
        for (int j = 0; j < 4; ++j) {
            int li = j * 256 + tid;      // dest slot li&7, row li>>3
            int row = li >> 3;
            int gslot = (li & 7) ^ (row & 7);
            gload_lds16(WbT + (size_t)(bcol + row) * 64 + gslot * 8, &Bs[li * 8]);
        }
    }
    __syncthreads();

    // phase 1b: MFMA  (Eb tile = edges x Wb^T, K = 64)
    f32x4 acc[4][4] = {};
#pragma unroll
    for (int k0 = 0; k0 < 64; k0 += 32) {
        bf16x8 af[4], bv[4];
#pragma unroll
        for (int m = 0; m < 4; ++m) {
            const int row = wr * 64 + m * 16 + (lane & 15);
            const int slot = ((k0 >> 3) + (lane >> 4)) ^ (row & 7);
            af[m] = *(const bf16x8*)&As[row * 64 + slot * 8];
        }
#pragma unroll
        for (int n = 0; n < 4; ++n) {
            const int row = wc * 64 + n * 16 + (lane & 15);
            const int slot = ((k0 >> 3) + (lane >> 4)) ^ (row & 7);
            bv[n] = *(const bf16x8*)&Bs[row * 64 + slot * 8];
        }
#pragma unroll
        for (int m = 0; m < 4; ++m)
#pragma unroll
            for (int n = 0; n < 4; ++n)
                acc[m][n] = __builtin_amdgcn_mfma_f32_16x16x32_bf16(af[m], bv[n], acc[m][n], 0, 0, 0);
    }
    __syncthreads();

    // phase 2: acc -> Eb LDS (bf16, stride 136)
    const int rowSub = wr * 64 + (lane >> 4) * 4;
#pragma unroll
    for (int m = 0; m < 4; ++m)
#pragma unroll
        for (int n = 0; n < 4; ++n)
#pragma unroll
            for (int i = 0; i < 4; ++i)
                smem[(rowSub + m * 16 + i) * 136 + wc * 64 + n * 16 + (lane & 15)] =
                    f2bf(acc[m][n][i]);
    __syncthreads();

    // phase 3: gather-add, row-coalesced (16 lanes = one edge row's 128 cols)
#pragma unroll
    for (int it = 0; it < 8; ++it) {
        int lin = it * 256 + tid;        // 0..2047
        int r = lin >> 4;                // 0..127
        int q = (lin & 15) * 8;          // 0..120
        int e = e0 + brow + r;
        int s = src[e];
        int t = tgt[e];
        int g = e >> 11;
        int col = bcol + q;
        u16x8 pa = *(const u16x8*)(Pac + (size_t)s * 1024 + col);
        u16x8 pc = *(const u16x8*)(Pac + (size_t)t * 1024 + 512 + col);
        u16x8 eb = *(const u16x8*)&smem[r * 136 + q];
        f32x4 g0 = *(const f32x4*)(Gdb + (size_t)g * 512 + col);
        f32x4 g1 = *(const f32x4*)(Gdb + (size_t)g * 512 + col + 4);
        u16x8 o;
#pragma unroll
        for (int j = 0; j < 8; ++j) {
            float gd = (j < 4) ? g0[j] : g1[j - 4];
            float v = b2f(pa[j]) + b2f(pc[j]) + b2f(eb[j]) + gd;
            o[j] = f2bf(fmaxf(v, 0.0f));
        }
        *(u16x8*)(h1 + (size_t)(brow + r) * 512 + col) = o;
    }
}

// ---------------- scatter-max: aggr[n,f] = max over edges with tgt==n --------------
// ONE launch over all graphs (msg buffer is full-size); 256 blocks, full GPU.
// block = (graph, 64-feat chunk); 64 edge-lanes x 16 feat-groups; u16x4 loads.

__global__ __launch_bounds__(1024) void scatter_max_kernel(
    const u16* __restrict__ msg, const int* __restrict__ tgt,
    u16* __restrict__ aggr) {
    int g = blockIdx.x >> 2;
    int fc = blockIdx.x & 3;
    __shared__ unsigned smax[256 * 64];  // 64 KiB
    int tid = threadIdx.x;
    for (int i = tid; i < 256 * 64; i += 1024) smax[i] = 0u;
    __syncthreads();
    const int eg = g * 2048;
    const int n0 = g * 256;
    const int f4 = (tid & 15) * 4;       // feat offset 0..60
    const int elane = tid >> 4;          // 0..63
    const u16* mbase = msg + fc * 64 + f4;
#pragma unroll
    for (int wv = 0; wv < 32; wv += 4) {
        const int e = eg + elane + wv * 64;
        int t0 = tgt[e], t1 = tgt[e + 64], t2 = tgt[e + 128], t3 = tgt[e + 192];
        u16x4 m0 = *(const u16x4*)(mbase + (size_t)e * 256);
        u16x4 m1 = *(const u16x4*)(mbase + (size_t)(e + 64) * 256);
        u16x4 m2 = *(const u16x4*)(mbase + (size_t)(e + 128) * 256);
        u16x4 m3 = *(const u16x4*)(mbase + (size_t)(e + 192) * 256);
        int a0 = t0 - n0, a1 = t1 - n0, a2 = t2 - n0, a3 = t3 - n0;
        if ((unsigned)a0 < 256u) {
            atomicMax(&smax[a0 * 64 + f4],     ((unsigned)m0.x) << 16);
            atomicMax(&smax[a0 * 64 + f4 + 1], ((unsigned)m0.y) << 16);
            atomicMax(&smax[a0 * 64 + f4 + 2], ((unsigned)m0.z) << 16);
            atomicMax(&smax[a0 * 64 + f4 + 3], ((unsigned)m0.w) << 16);
        }
        if ((unsigned)a1 < 256u) {
            atomicMax(&smax[a1 * 64 + f4],     ((unsigned)m1.x) << 16);
            atomicMax(&smax[a1 * 64 + f4 + 1], ((unsigned)m1.y) << 16);
            atomicMax(&smax[a1 * 64 + f4 + 2], ((unsigned)m1.z) << 16);
            atomicMax(&smax[a1 * 64 + f4 + 3], ((unsigned)m1.w) << 16);
        }
        if ((unsigned)a2 < 256u) {
            atomicMax(&smax[a2 * 64 + f4],     ((unsigned)m2.x) << 16);
            atomicMax(&smax[a2 * 64 + f4 + 1], ((unsigned)m2.y) << 16);
            atomicMax(&smax[a2 * 64 + f4 + 2], ((unsigned)m2.z) << 16);
            atomicMax(&smax[a2 * 64 + f4 + 3], ((unsigned)m2.w) << 16);
        }
        if ((unsigned)a3 < 256u) {
            atomicMax(&smax[a3 * 64 + f4],     ((unsigned)m3.x) << 16);
            atomicMax(&smax[a3 * 64 + f4 + 1], ((unsigned)m3.y) << 16);
            atomicMax(&smax[a3 * 64 + f4 + 2], ((unsigned)m3.z) << 16);
            atomicMax(&smax[a3 * 64 + f4 + 3], ((unsigned)m3.w) << 16);
        }
    }
    __syncthreads();
    for (int i = tid; i < 256 * 64; i += 1024) {
        int nl = i >> 6, ff = i & 63;
        aggr[(size_t)(n0 + nl) * 256 + fc * 64 + ff] = (u16)(smax[nl * 64 + ff] >> 16);
    }
}

// ---------------- merged head: agg_nodes + glob matvec + action softmax ------------

__global__ __launch_bounds__(256) void head_kernel(
    const u16* __restrict__ h, const float* __restrict__ glob,
    const float* __restrict__ W, const float* __restrict__ b,
    const float* __restrict__ actw, const float* __restrict__ actb,
    float* __restrict__ out_act) {
    int g = blockIdx.x;
    int tid = threadIdx.x;
    __shared__ float in[384];
    __shared__ float go[256];
    __shared__ float logits[8];
    // phase A: per-feature max over the graph's 256 nodes
    {
        const size_t base = (size_t)g * 256 * 256 + tid;
        float m0 = 0.0f, m1 = 0.0f, m2 = 0.0f, m3 = 0.0f;
        for (int n = 0; n < 256; n += 4) {
            m0 = fmaxf(m0, b2f(h[base + (size_t)n * 256]));
            m1 = fmaxf(m1, b2f(h[base + (size_t)(n + 1) * 256]));
            m2 = fmaxf(m2, b2f(h[base + (size_t)(n + 2) * 256]));
            m3 = fmaxf(m3, b2f(h[base + (size_t)(n + 3) * 256]));
        }
        in[tid] = fmaxf(fmaxf(m0, m1), fmaxf(m2, m3));
        if (tid < 128) in[256 + tid] = glob[(size_t)g * 128 + tid];
    }
    __syncthreads();
    // phase B: gout = relu([agg | glob] @ W + b)
    {
        float s = b[tid];
        for (int k = 0; k < 384; ++k) s += in[k] * W[(size_t)k * 256 + tid];
        go[tid] = fmaxf(s, 0.0f);
    }
    __syncthreads();
    // phase C: action = softmax(go @ actw + actb)
    if (tid < 8) {
        float s = actb[tid];
        for (int k = 0; k < 256; ++k) s += go[k] * actw[(size_t)k * 8 + tid];
        logits[tid] = s;
    }
    __syncthreads();
    if (tid == 0) {
        float mx = logits[0];
        for (int i = 1; i < 8; ++i) mx = fmaxf(mx, logits[i]);
        float ex[8], den = 0.0f;
        for (int i = 0; i < 8; ++i) { ex[i] = expf(logits[i] - mx); den += ex[i]; }
        float inv = 1.0f / den;
        for (int i = 0; i < 8; ++i) out_act[(size_t)g * 8 + i] = ex[i] * inv;
    }
}

// ---------------- workspace layout ----------------

constexpr size_t OFF_NODES_BF = 0;                                    // 8388608
constexpr size_t OFF_GLOB_BF  = OFF_NODES_BF + (size_t)TNN * TFN * 2; // 16384
constexpr size_t OFF_WACT = OFF_GLOB_BF + (size_t)TNG * TFG * 2;      // 1024*256*2
constexpr size_t OFF_WBT  = OFF_WACT + 1024 * 256 * 2;                // 512*64*2
constexpr size_t OFF_W1T  = OFF_WBT + 512 * 64 * 2;                   // 512*512*2
constexpr size_t OFF_W2T  = OFF_W1T + 512 * 512 * 2;                  // 256*512*2
constexpr size_t OFF_U0T  = OFF_W2T + 256 * 512 * 2;                  // 512*640*2
constexpr size_t OFF_U1T  = OFF_U0T + 512 * 640 * 2;                  // 256*512*2
constexpr size_t OFF_EMBT = OFF_U1T + 256 * 512 * 2;                  // 128*256*2
constexpr size_t OFF_AGGR = OFF_EMBT + 128 * 256 * 2;                 // 16384*256*2
constexpr size_t OFF_GDB  = OFF_AGGR + (size_t)TNN * 256 * 2;         // 64*512*4
constexpr size_t OFF_PAC  = OFF_GDB + 64 * 512 * 4;                   // 16384*1024*2
constexpr size_t OFF_MSG  = OFF_PAC + (size_t)TNN * 1024 * 2;         // full msg: TNE*256*2
constexpr size_t OFF_V    = OFF_MSG + (size_t)TNE * 256 * 2;          // chunked h1c/h2c
constexpr size_t SZ_HU1   = (size_t)TNN * 512 * 2;

extern "C" void kernel_launch(void* const* d_in, const int* in_sizes, int n_in,
                              void* d_out, int out_size, void* d_ws, size_t ws_size,
                              hipStream_t stream) {
    const float* nodes       = (const float*)d_in[0];
    const float* edge_attr   = (const float*)d_in[1];
    const float* global_attr = (const float*)d_in[2];
    const int*   edge_idx    = (const int*)d_in[3];
    const float* msg_w0 = (const float*)d_in[7];
    const float* msg_b0 = (const float*)d_in[8];
    const float* msg_w1 = (const float*)d_in[9];
    const float* msg_b1 = (const float*)d_in[10];
    const float* msg_w2 = (const float*)d_in[11];
    const float* msg_b2 = (const float*)d_in[12];
    const float* upd_w0 = (const float*)d_in[13];
    const float* upd_b0 = (const float*)d_in[14];
    const float* upd_w1 = (const float*)d_in[15];
    const float* upd_b1 = (const float*)d_in[16];
    const float* glob_w = (const float*)d_in[17];
    const float* glob_b = (const float*)d_in[18];
    const float* emb_w  = (const float*)d_in[19];
    const float* emb_b  = (const float*)d_in[20];
    const float* act_w  = (const float*)d_in[21];
    const float* act_b  = (const float*)d_in[22];

    const int* src = edge_idx;
    const int* tgt = edge_idx + TNE;

    char* ws = (char*)d_ws;
    u16* nodes_bf = (u16*)(ws + OFF_NODES_BF);
    u16* glob_bf  = (u16*)(ws + OFF_GLOB_BF);
    u16* WacT = (u16*)(ws + OFF_WACT);
    u16* WbT  = (u16*)(ws + OFF_WBT);
    u16* W1T  = (u16*)(ws + OFF_W1T);
    u16* W2T  = (u16*)(ws + OFF_W2T);
    u16* U0T  = (u16*)(ws + OFF_U0T);
    u16* U1T  = (u16*)(ws + OFF_U1T);
    u16* EmbT = (u16*)(ws + OFF_EMBT);
    u16* aggr = (u16*)(ws + OFF_AGGR);
    float* Gdb = (float*)(ws + OFF_GDB);
    u16* Pac  = (u16*)(ws + OFF_PAC);
    u16* msgc = (u16*)(ws + OFF_MSG);
    float* out = (float*)d_out;

    // chunk size: CH=32768 keeps {Pac, h1c, h2c, msgc, aggr, weights} inside the
    // 256 MB L3 (~185 MB live). Halve if ws is tight (historical ws >= 388 MB).
    size_t CH = 32768;
    while (CH > 2048 && OFF_V + CH * 2048 > ws_size) CH >>= 1;
    const int nchunk = (int)((size_t)TNE / CH);

    u16* h1c  = (u16*)(ws + OFF_V);
    u16* h2c  = (u16*)(ws + OFF_V + CH * 1024);
    u16* hu1  = (u16*)(ws + OFF_V);            // node phase (edge buffers dead)
    u16* h_bf = (u16*)(ws + OFF_AGGR);         // overlays aggr (dead after U0)

    // ---- setup ----
    cast_kernel<<<(TNN * TFN / 4 + 255) / 256, 256, 0, stream>>>(nodes, nodes_bf, TNN * TFN / 4);

    PrepTab tab;
    int ntiles = 0;
    {
        const float* Ws[8]  = {msg_w0, msg_w0, msg_w0, msg_w1, msg_w2, upd_w0, upd_w1, emb_w};
        int offs[8] = {(int)(OFF_WACT / 2), (int)(OFF_WACT / 2) + 131072, (int)(OFF_WBT / 2),
                       (int)(OFF_W1T / 2), (int)(OFF_W2T / 2), (int)(OFF_U0T / 2),
                       (int)(OFF_U1T / 2), (int)(OFF_EMBT / 2)};
        int nin[8]  = {512, 512, 512, 512, 256, 512, 256, 64};
        int nact[8] = {512, 512, 512, 512, 256, 512, 256, 64};
        int r0v[8]  = {0, 320, 256, 0, 0, 0, 0, 0};
        int ksub[8] = {256, 256, 64, 512, 512, 640, 512, 256};
        int npad[8] = {512, 512, 512, 512, 256, 512, 256, 128};
        int acc = 0;
        for (int i = 0; i < 8; ++i) {
            tab.W[i] = Ws[i]; tab.out_off[i] = offs[i]; tab.Nin[i] = nin[i];
            tab.Nact[i] = nact[i]; tab.r0[i] = r0v[i]; tab.Ksub[i] = ksub[i];
            tab.tkn[i] = ksub[i] / 64;
            tab.tile0[i] = acc;
            acc += (npad[i] / 64) * (ksub[i] / 64);
        }
        ntiles = acc;   // 288
    }
    prep_weights_kernel<<<ntiles, 256, 0, stream>>>(tab, (u16*)ws);
    gd_kernel<<<64, 256, 0, stream>>>(global_attr, msg_w0, msg_b0, Gdb, glob_bf);

    // Pac = nodes_bf @ [Wa | Wc]^T   (M=16384, N=1024, K=256)
    gemm_bt_kernel<256, 3, false, true><<<1024, 256, 0, stream>>>(nodes_bf, WacT, nullptr, Pac, 1024, 1024);

    // ---- edge pipeline (chunked for L3 residency); scatter once at the end ----
    for (int ci = 0; ci < nchunk; ++ci) {
        const int e0 = (int)(ci * CH);
        const int nwg = (int)(CH / 32);   // 4 * CH/128
        h1_fused_kernel<<<nwg, 256, 0, stream>>>(
            edge_attr, WbT, Pac, Gdb, src, tgt, h1c, e0);
        gemm_bt_kernel<512, 2, true, true><<<nwg, 256, 0, stream>>>(h1c, W1T, msg_b1, h2c, 512, 512);
        gemm_bt_kernel<512, 1, true, true><<<nwg / 2, 256, 0, stream>>>(
            h2c, W2T, msg_b2, msgc + (size_t)e0 * 256, 256, 256);
    }
    scatter_max_kernel<<<TNG * 4, 1024, 0, stream>>>(msgc, tgt, aggr);

    // ---- node update MLP (concat fused into U0 staging) ----
    gemm_u0_kernel<<<512, 256, 0, stream>>>(nodes_bf, aggr, glob_bf, U0T, upd_b0, hu1);
    gemm_bt_kernel<512, 1, true, true><<<256, 256, 0, stream>>>(hu1, U1T, upd_b1, h_bf, 256, 256);

    // ---- heads ----
    head_kernel<<<64, 256, 0, stream>>>(h_bf, global_attr, glob_w, glob_b,
                                        act_w, act_b, out + (size_t)TNN * 64);
    gemm_bt_kernel<256, 0, true, false><<<128, 256, 0, stream>>>(h_bf, EmbT, emb_b, out, 64, 64);

    (void)in_sizes; (void)n_in; (void)out_size;
}

// Round 10
// 343.643 us; speedup vs baseline: 1.1044x; 1.0148x over previous
//
#include <hip/hip_runtime.h>
#include <hip/hip_bf16.h>

typedef unsigned short u16;
using u16x4 = __attribute__((ext_vector_type(4))) unsigned short;
using u16x8 = __attribute__((ext_vector_type(8))) unsigned short;
using u32x4 = __attribute__((ext_vector_type(4))) unsigned int;
using f32x4 = __attribute__((ext_vector_type(4))) float;
using bf16x8 = __attribute__((ext_vector_type(8))) __bf16;

#define TNG 64
#define TNN 16384
#define TNE 131072
#define TFN 256
#define TFE 64
#define TFG 128
// graphs are fixed-size: edge e -> graph e>>11, node n -> graph n>>8

__device__ __forceinline__ u16 f2bf(float f) {
    unsigned u = __float_as_uint(f);
    unsigned r = (u + 0x7FFFu + ((u >> 16) & 1u)) >> 16;
    return (u16)r;
}
__device__ __forceinline__ float b2f(u16 h) {
    return __uint_as_float(((unsigned)h) << 16);
}

// async global->LDS, 16B per lane (dest must be linear: base + lane*16)
__device__ __forceinline__ void gload_lds16(const u16* g, u16* l) {
    __builtin_amdgcn_global_load_lds(
        (const __attribute__((address_space(1))) void*)g,
        (__attribute__((address_space(3))) void*)l, 16, 0, 0);
}

// chunked XCD swizzle: nwg % 8 == 0 -> XCD k gets a contiguous work range
__device__ __forceinline__ int xcd_swz(int bid, int nwg) {
    return (nwg & 7) == 0 ? (bid & 7) * (nwg >> 3) + (bid >> 3) : bid;
}

// ---------------- setup: f32 -> bf16 cast ----------------

__global__ void cast_kernel(const float* __restrict__ in, u16* __restrict__ out, int n4) {
    int i = blockIdx.x * 256 + threadIdx.x;
    if (i >= n4) return;
    f32x4 v = *(const f32x4*)(in + (size_t)i * 4);
    u16x4 o;
    o.x = f2bf(v.x); o.y = f2bf(v.y); o.z = f2bf(v.z); o.w = f2bf(v.w);
    *(u16x4*)(out + (size_t)i * 4) = o;
}

// ---------------- weight transpose+cast via LDS 64x64 tiles (coalesced both sides) --
// out[n*Ksub + k] = (n < Nact) ? W[(r0+k)*Nin + n] : 0

struct PrepTab {
    const float* W[8];
    int out_off[8];   // u16 offset from ws base
    int Nin[8], Nact[8], r0[8], Ksub[8];
    int tile0[8];     // prefix sum of tile counts; tiles = (Npad/64)*(Ksub/64)
    int tkn[8];       // Ksub/64
};

__global__ __launch_bounds__(256) void prep_weights_kernel(PrepTab tab, u16* __restrict__ wsbase) {
    const int b = blockIdx.x;
    int i = 7;
#pragma unroll
    for (int j = 7; j > 0; --j)
        if (b < tab.tile0[j]) i = j - 1;
    const int loc = b - tab.tile0[i];
    const int tk = loc % tab.tkn[i];
    const int tn = loc / tab.tkn[i];
    const int kb = tk * 64, nb = tn * 64;
    const int Nin = tab.Nin[i], Nact = tab.Nact[i], r0 = tab.r0[i], Ksub = tab.Ksub[i];
    const float* W = tab.W[i];
    u16* outp = wsbase + tab.out_off[i];

    __shared__ float t[64][65];
    const int tid = threadIdx.x;
    const int nl = tid & 63;
    const bool nok = (nb + nl) < Nact;
#pragma unroll 4
    for (int kk = tid >> 6; kk < 64; kk += 4) {
        float v = nok ? W[(size_t)(r0 + kb + kk) * Nin + nb + nl] : 0.0f;
        t[kk][nl] = v;
    }
    __syncthreads();
    const int kl = tid & 63;
#pragma unroll 4
    for (int nn = tid >> 6; nn < 64; nn += 4)
        outp[(size_t)(nb + nn) * Ksub + kb + kl] = f2bf(t[kl][nn]);
}

// ---------------- bf16 MFMA GEMM: C = act(A[M,K] @ Bt[N,K]^T + bias) ----------------
// Depth-3 counted-vmcnt pipeline: 4 LDS buffers, prefetch distance 3, ONE raw
// s_barrier per K-step, s_waitcnt vmcnt(8) in-loop (2 stages in flight; never 0
// until the tail). Issue-to-use lead = ~2 K-steps, covering L2/L3/HBM latency.
// Safety: stage(t+3) writes buf (t-1)&3 whose readers all passed barrier(t) before
// the stage issues; vmcnt(8) at iter t completes stage(t) (oldest beyond 8).
// Bank swizzle: LDS(row, s) holds global slot s ^ ((row>>1)&3)  [both sides, rule #21]

template <int K, int NXSH, bool RELU, bool OUT_BF16>
__global__ __launch_bounds__(256) void gemm_bt_kernel(
    const u16* __restrict__ A, const u16* __restrict__ Bt,
    const float* __restrict__ bias, void* __restrict__ Cv,
    int Nout, int ldc) {
    constexpr int NT = K / 32;
    __shared__ u16 As[4][4096];
    __shared__ u16 Bs[4][4096];
    const int w = xcd_swz(blockIdx.x, gridDim.x);
    const int bxi = w & ((1 << NXSH) - 1);
    const int byi = w >> NXSH;
    const int tid = threadIdx.x;
    const int wave = tid >> 6, lane = tid & 63;
    const int wr = wave >> 1, wc = wave & 1;
    const size_t brow = (size_t)byi * 128;
    const size_t bcol = (size_t)bxi * 128;
    const int srow = tid >> 2;
    const int qsrc = (tid & 3) ^ ((srow >> 1) & 3);   // swizzled source slot
    const u16* aSrc = A + (brow + srow) * (size_t)K + qsrc * 8;
    const u16* bSrc = Bt + (bcol + srow) * (size_t)K + qsrc * 8;
    const size_t stepRows = (size_t)64 * K;

    auto stage = [&](int t, int buf) {
        const int k0 = t * 32;
        gload_lds16(aSrc + k0, &As[buf][tid * 8]);
        gload_lds16(aSrc + stepRows + k0, &As[buf][tid * 8 + 2048]);
        gload_lds16(bSrc + k0, &Bs[buf][tid * 8]);
        gload_lds16(bSrc + stepRows + k0, &Bs[buf][tid * 8 + 2048]);
    };

    f32x4 acc[4][4] = {};

    stage(0, 0);
    stage(1, 1);
    stage(2, 2);
#pragma unroll
    for (int t = 0; t < NT; ++t) {
        const int cur = t & 3;
        if (t + 2 < NT)      asm volatile("s_waitcnt vmcnt(8)" ::: "memory");
        else if (t + 1 < NT) asm volatile("s_waitcnt vmcnt(4)" ::: "memory");
        else                 asm volatile("s_waitcnt vmcnt(0)" ::: "memory");
        __builtin_amdgcn_s_barrier();
        if (t + 3 < NT) stage(t + 3, (t + 3) & 3);
        bf16x8 af[4], bfv[4];
#pragma unroll
        for (int m = 0; m < 4; ++m) {
            const int row = wr * 64 + m * 16 + (lane & 15);
            const int slot = (lane >> 4) ^ ((row >> 1) & 3);
            af[m] = *(const bf16x8*)&As[cur][row * 32 + slot * 8];
        }
#pragma unroll
        for (int n = 0; n < 4; ++n) {
            const int row = wc * 64 + n * 16 + (lane & 15);
            const int slot = (lane >> 4) ^ ((row >> 1) & 3);
            bfv[n] = *(const bf16x8*)&Bs[cur][row * 32 + slot * 8];
        }
#pragma unroll
        for (int m = 0; m < 4; ++m)
#pragma unroll
            for (int n = 0; n < 4; ++n)
                acc[m][n] = __builtin_amdgcn_mfma_f32_16x16x32_bf16(af[m], bfv[n], acc[m][n], 0, 0, 0);
    }

    const int rowSub = wr * 64 + (lane >> 4) * 4;
#pragma unroll
    for (int n = 0; n < 4; ++n) {
        const int col = (int)bcol + wc * 64 + n * 16 + (lane & 15);
        if (col >= Nout) continue;
        const float bv = bias ? bias[col] : 0.0f;
#pragma unroll
        for (int m = 0; m < 4; ++m) {
#pragma unroll
            for (int i = 0; i < 4; ++i) {
                float v = acc[m][n][i] + bv;
                if (RELU) v = fmaxf(v, 0.0f);
                size_t off = (brow + rowSub + m * 16 + i) * (size_t)ldc + col;
                if (OUT_BF16) ((u16*)Cv)[off] = f2bf(v);
                else ((float*)Cv)[off] = v;
            }
        }
    }
}

// ---------------- U0 GEMM with fused concat staging (depth-3 pipeline) -------------
// virtual A[row][640] = [nodes_bf(256) | aggr(256) | glob_bf[row>>8](128)]

__global__ __launch_bounds__(256) void gemm_u0_kernel(
    const u16* __restrict__ nodes_bf, const u16* __restrict__ aggr,
    const u16* __restrict__ glob_bf, const u16* __restrict__ U0T,
    const float* __restrict__ bias, u16* __restrict__ C) {
    constexpr int NT = 20;
    __shared__ u16 As[4][4096];
    __shared__ u16 Bs[4][4096];
    const int w = xcd_swz(blockIdx.x, gridDim.x);
    const int bxi = w & 3;
    const int byi = w >> 2;
    const int tid = threadIdx.x;
    const int wave = tid >> 6, lane = tid & 63;
    const int wr = wave >> 1, wc = wave & 1;
    const size_t brow = (size_t)byi * 128;
    const size_t bcol = (size_t)bxi * 128;
    const int srow = tid >> 2;
    const int scol = ((tid & 3) ^ ((srow >> 1) & 3)) * 8;   // swizzled source col
    const int r0i = (int)brow + srow;
    const u16* bSrc = U0T + (bcol + srow) * (size_t)640 + scol;

    auto stage = [&](int t, int buf) {
        const int k0 = t * 32;
        const u16 *p0, *p1;
        if (k0 < 256) {
            p0 = nodes_bf + (size_t)r0i * 256 + k0 + scol;
            p1 = nodes_bf + (size_t)(r0i + 64) * 256 + k0 + scol;
        } else if (k0 < 512) {
            p0 = aggr + (size_t)r0i * 256 + (k0 - 256) + scol;
            p1 = aggr + (size_t)(r0i + 64) * 256 + (k0 - 256) + scol;
        } else {
            p0 = glob_bf + (size_t)(r0i >> 8) * 128 + (k0 - 512) + scol;
            p1 = glob_bf + (size_t)((r0i + 64) >> 8) * 128 + (k0 - 512) + scol;
        }
        gload_lds16(p0, &As[buf][tid * 8]);
        gload_lds16(p1, &As[buf][tid * 8 + 2048]);
        gload_lds16(bSrc + k0, &Bs[buf][tid * 8]);
        gload_lds16(bSrc + (size_t)64 * 640 + k0, &Bs[buf][tid * 8 + 2048]);
    };

    f32x4 acc[4][4] = {};

    stage(0, 0);
    stage(1, 1);
    stage(2, 2);
#pragma unroll
    for (int t = 0; t < NT; ++t) {
        const int cur = t & 3;
        if (t + 2 < NT)      asm volatile("s_waitcnt vmcnt(8)" ::: "memory");
        else if (t + 1 < NT) asm volatile("s_waitcnt vmcnt(4)" ::: "memory");
        else                 asm volatile("s_waitcnt vmcnt(0)" ::: "memory");
        __builtin_amdgcn_s_barrier();
        if (t + 3 < NT) stage(t + 3, (t + 3) & 3);
        bf16x8 af[4], bfv[4];
#pragma unroll
        for (int m = 0; m < 4; ++m) {
            const int row = wr * 64 + m * 16 + (lane & 15);
            const int slot = (lane >> 4) ^ ((row >> 1) & 3);
            af[m] = *(const bf16x8*)&As[cur][row * 32 + slot * 8];
        }
#pragma unroll
        for (int n = 0; n < 4; ++n) {
            const int row = wc * 64 + n * 16 + (lane & 15);
            const int slot = (lane >> 4) ^ ((row >> 1) & 3);
            bfv[n] = *(const bf16x8*)&Bs[cur][row * 32 + slot * 8];
        }
#pragma unroll
        for (int m = 0; m < 4; ++m)
#pragma unroll
            for (int n = 0; n < 4; ++n)
                acc[m][n] = __builtin_amdgcn_mfma_f32_16x16x32_bf16(af[m], bfv[n], acc[m][n], 0, 0, 0);
    }

    const int rowSub = wr * 64 + (lane >> 4) * 4;
#pragma unroll
    for (int n = 0; n < 4; ++n) {
        const int col = (int)bcol + wc * 64 + n * 16 + (lane & 15);
        const float bv = bias[col];
#pragma unroll
        for (int m = 0; m < 4; ++m)
#pragma unroll
            for (int i = 0; i < 4; ++i) {
                float v = fmaxf(acc[m][n][i] + bv, 0.0f);
                C[(brow + rowSub + m * 16 + i) * (size_t)512 + col] = f2bf(v);
            }
    }
}

// ---------------- Gdb = global_attr @ msg_w0[576:704] + b0; also glob_bf ----------

__global__ __launch_bounds__(256) void gd_kernel(const float* __restrict__ glob,
                                                 const float* __restrict__ msg_w0,
                                                 const float* __restrict__ b0,
                                                 float* __restrict__ Gdb,
                                                 u16* __restrict__ glob_bf) {
    int g = blockIdx.x;
    __shared__ float in[TFG];
    if (threadIdx.x < TFG) {
        float v = glob[g * TFG + threadIdx.x];
        in[threadIdx.x] = v;
        glob_bf[g * TFG + threadIdx.x] = f2bf(v);
    }
    __syncthreads();
    for (int j = threadIdx.x; j < 512; j += 256) {
        float s = b0[j];
        for (int k = 0; k < TFG; ++k) s += in[k] * msg_w0[(size_t)(576 + k) * 512 + j];
        Gdb[(size_t)g * 512 + j] = s;
    }
}

// ---------------- fused layer-1: h1 = relu(Ef@Wb + Pac[s] + Pac[t,512+] + Gdb) ----
// [128][64] tiles, 8 slots/row, swizzle slot ^= (row&7) (16-way -> 2-way conflicts)

__global__ __launch_bounds__(256) void h1_fused_kernel(
    const float* __restrict__ Ef, const u16* __restrict__ WbT,
    const u16* __restrict__ Pac, const float* __restrict__ Gdb,
    const int* __restrict__ src, const int* __restrict__ tgt,
    u16* __restrict__ h1, int e0) {
    __shared__ u16 smem[17408];          // As[0..8192) | Bs[8192..16384); Eb overlays (stride 136)
    u16* As = smem;
    u16* Bs = smem + 8192;
    const int w = xcd_swz(blockIdx.x, gridDim.x);
    const int bxi = w & 3;
    const int byi = w >> 2;
    const int tid = threadIdx.x;
    const int wave = tid >> 6, lane = tid & 63;
    const int wr = wave >> 1, wc = wave & 1;
    const int brow = byi * 128;
    const int bcol = bxi * 128;

    // phase 1a: stage edge tile (f32 -> bf16, swizzled dest slots) + Wb (gload,
    // swizzled source slot)
    {
        const int r = tid >> 2;
        const int cq = (tid & 3) * 2;    // global slots cq, cq+1 (8 u16 each)
        const int sw = r & 7;
#pragma unroll
        for (int h = 0; h < 2; ++h) {
            const float* sp = Ef + (size_t)(e0 + brow + r + h * 64) * 64 + cq * 8;
            f32x4 v0 = *(const f32x4*)(sp);
            f32x4 v1 = *(const f32x4*)(sp + 4);
            f32x4 v2 = *(const f32x4*)(sp + 8);
            f32x4 v3 = *(const f32x4*)(sp + 12);
            u16x8 o0, o1;
            o0[0] = f2bf(v0.x); o0[1] = f2bf(v0.y); o0[2] = f2bf(v0.z); o0[3] = f2bf(v0.w);
            o0[4] = f2bf(v1.x); o0[5] = f2bf(v1.y); o0[6] = f2bf(v1.z); o0[7] = f2bf(v1.w);
            o1[0] = f2bf(v2.x); o1[1] = f2bf(v2.y); o1[2] = f2bf(v2.z); o1[3] = f2bf(v2.w);
            o1[4] = f2bf(v3.x); o1[5] = f2bf(v3.y); o1[6] = f2bf(v3.z); o1[7] = f2bf(v3.w);
            *(u16x8*)&As[(r + h * 64) * 64 + (cq ^ sw) * 8] = o0;
            *(u16x8*)&As[(r + h * 64) * 64 + ((cq + 1) ^ sw) * 8] = o1;
        }
#pragma unroll
        for (int j = 0; j < 4; ++j) {
            int li = j * 256 + tid;      // dest slot li&7, row li>>3
            int row = li >> 3;
            int gslot = (li & 7) ^ (row & 7);
            gload_lds16(WbT + (size_t)(bcol + row) * 64 + gslot * 8, &Bs[li * 8]);
        }
    }
    __syncthreads();

    // phase 1b: MFMA  (Eb tile = edges x Wb^T, K = 64)
    f32x4 acc[4][4] = {};
#pragma unroll
    for (int k0 = 0; k0 < 64; k0 += 32) {
        bf16x8 af[4], bv[4];
#pragma unroll
        for (int m = 0; m < 4; ++m) {
            const int row = wr * 64 + m * 16 + (lane & 15);
            const int slot = ((k0 >> 3) + (lane >> 4)) ^ (row & 7);
            af[m] = *(const bf16x8*)&As[row * 64 + slot * 8];
        }
#pragma unroll
        for (int n = 0; n < 4; ++n) {
            const int row = wc * 64 + n * 16 + (lane & 15);
            const int slot = ((k0 >> 3) + (lane >> 4)) ^ (row & 7);
            bv[n] = *(const bf16x8*)&Bs[row * 64 + slot * 8];
        }
#pragma unroll
        for (int m = 0; m < 4; ++m)
#pragma unroll
            for (int n = 0; n < 4; ++n)
                acc[m][n] = __builtin_amdgcn_mfma_f32_16x16x32_bf16(af[m], bv[n], acc[m][n], 0, 0, 0);
    }
    __syncthreads();

    // phase 2: acc -> Eb LDS (bf16, stride 136)
    const int rowSub = wr * 64 + (lane >> 4) * 4;
#pragma unroll
    for (int m = 0; m < 4; ++m)
#pragma unroll
        for (int n = 0; n < 4; ++n)
#pragma unroll
            for (int i = 0; i < 4; ++i)
                smem[(rowSub + m * 16 + i) * 136 + wc * 64 + n * 16 + (lane & 15)] =
                    f2bf(acc[m][n][i]);
    __syncthreads();

    // phase 3: gather-add, row-coalesced (16 lanes = one edge row's 128 cols)
#pragma unroll
    for (int it = 0; it < 8; ++it) {
        int lin = it * 256 + tid;        // 0..2047
        int r = lin >> 4;                // 0..127
        int q = (lin & 15) * 8;          // 0..120
        int e = e0 + brow + r;
        int s = src[e];
        int t = tgt[e];
        int g = e >> 11;
        int col = bcol + q;
        u16x8 pa = *(const u16x8*)(Pac + (size_t)s * 1024 + col);
        u16x8 pc = *(const u16x8*)(Pac + (size_t)t * 1024 + 512 + col);
        u16x8 eb = *(const u16x8*)&smem[r * 136 + q];
        f32x4 g0 = *(const f32x4*)(Gdb + (size_t)g * 512 + col);
        f32x4 g1 = *(const f32x4*)(Gdb + (size_t)g * 512 + col + 4);
        u16x8 o;
#pragma unroll
        for (int j = 0; j < 8; ++j) {
            float gd = (j < 4) ? g0[j] : g1[j - 4];
            float v = b2f(pa[j]) + b2f(pc[j]) + b2f(eb[j]) + gd;
            o[j] = f2bf(fmaxf(v, 0.0f));
        }
        *(u16x8*)(h1 + (size_t)(brow + r) * 512 + col) = o;
    }
}

// ---------------- scatter-max: aggr[n,f] = max over edges with tgt==n --------------
// ONE launch over all graphs (msg buffer is full-size); 256 blocks, full GPU.
// block = (graph, 64-feat chunk); 64 edge-lanes x 16 feat-groups; u16x4 loads.

__global__ __launch_bounds__(1024) void scatter_max_kernel(
    const u16* __restrict__ msg, const int* __restrict__ tgt,
    u16* __restrict__ aggr) {
    int g = blockIdx.x >> 2;
    int fc = blockIdx.x & 3;
    __shared__ unsigned smax[256 * 64];  // 64 KiB
    int tid = threadIdx.x;
    for (int i = tid; i < 256 * 64; i += 1024) smax[i] = 0u;
    __syncthreads();
    const int eg = g * 2048;
    const int n0 = g * 256;
    const int f4 = (tid & 15) * 4;       // feat offset 0..60
    const int elane = tid >> 4;          // 0..63
    const u16* mbase = msg + fc * 64 + f4;
#pragma unroll
    for (int wv = 0; wv < 32; wv += 4) {
        const int e = eg + elane + wv * 64;
        int t0 = tgt[e], t1 = tgt[e + 64], t2 = tgt[e + 128], t3 = tgt[e + 192];
        u16x4 m0 = *(const u16x4*)(mbase + (size_t)e * 256);
        u16x4 m1 = *(const u16x4*)(mbase + (size_t)(e + 64) * 256);
        u16x4 m2 = *(const u16x4*)(mbase + (size_t)(e + 128) * 256);
        u16x4 m3 = *(const u16x4*)(mbase + (size_t)(e + 192) * 256);
        int a0 = t0 - n0, a1 = t1 - n0, a2 = t2 - n0, a3 = t3 - n0;
        if ((unsigned)a0 < 256u) {
            atomicMax(&smax[a0 * 64 + f4],     ((unsigned)m0.x) << 16);
            atomicMax(&smax[a0 * 64 + f4 + 1], ((unsigned)m0.y) << 16);
            atomicMax(&smax[a0 * 64 + f4 + 2], ((unsigned)m0.z) << 16);
            atomicMax(&smax[a0 * 64 + f4 + 3], ((unsigned)m0.w) << 16);
        }
        if ((unsigned)a1 < 256u) {
            atomicMax(&smax[a1 * 64 + f4],     ((unsigned)m1.x) << 16);
            atomicMax(&smax[a1 * 64 + f4 + 1], ((unsigned)m1.y) << 16);
            atomicMax(&smax[a1 * 64 + f4 + 2], ((unsigned)m1.z) << 16);
            atomicMax(&smax[a1 * 64 + f4 + 3], ((unsigned)m1.w) << 16);
        }
        if ((unsigned)a2 < 256u) {
            atomicMax(&smax[a2 * 64 + f4],     ((unsigned)m2.x) << 16);
            atomicMax(&smax[a2 * 64 + f4 + 1], ((unsigned)m2.y) << 16);
            atomicMax(&smax[a2 * 64 + f4 + 2], ((unsigned)m2.z) << 16);
            atomicMax(&smax[a2 * 64 + f4 + 3], ((unsigned)m2.w) << 16);
        }
        if ((unsigned)a3 < 256u) {
            atomicMax(&smax[a3 * 64 + f4],     ((unsigned)m3.x) << 16);
            atomicMax(&smax[a3 * 64 + f4 + 1], ((unsigned)m3.y) << 16);
            atomicMax(&smax[a3 * 64 + f4 + 2], ((unsigned)m3.z) << 16);
            atomicMax(&smax[a3 * 64 + f4 + 3], ((unsigned)m3.w) << 16);
        }
    }
    __syncthreads();
    for (int i = tid; i < 256 * 64; i += 1024) {
        int nl = i >> 6, ff = i & 63;
        aggr[(size_t)(n0 + nl) * 256 + fc * 64 + ff] = (u16)(smax[nl * 64 + ff] >> 16);
    }
}

// ---------------- merged head: agg_nodes + glob matvec + action softmax ------------

__global__ __launch_bounds__(256) void head_kernel(
    const u16* __restrict__ h, const float* __restrict__ glob,
    const float* __restrict__ W, const float* __restrict__ b,
    const float* __restrict__ actw, const float* __restrict__ actb,
    float* __restrict__ out_act) {
    int g = blockIdx.x;
    int tid = threadIdx.x;
    __shared__ float in[384];
    __shared__ float go[256];
    __shared__ float logits[8];
    // phase A: per-feature max over the graph's 256 nodes
    {
        const size_t base = (size_t)g * 256 * 256 + tid;
        float m0 = 0.0f, m1 = 0.0f, m2 = 0.0f, m3 = 0.0f;
        for (int n = 0; n < 256; n += 4) {
            m0 = fmaxf(m0, b2f(h[base + (size_t)n * 256]));
            m1 = fmaxf(m1, b2f(h[base + (size_t)(n + 1) * 256]));
            m2 = fmaxf(m2, b2f(h[base + (size_t)(n + 2) * 256]));
            m3 = fmaxf(m3, b2f(h[base + (size_t)(n + 3) * 256]));
        }
        in[tid] = fmaxf(fmaxf(m0, m1), fmaxf(m2, m3));
        if (tid < 128) in[256 + tid] = glob[(size_t)g * 128 + tid];
    }
    __syncthreads();
    // phase B: gout = relu([agg | glob] @ W + b)
    {
        float s = b[tid];
        for (int k = 0; k < 384; ++k) s += in[k] * W[(size_t)k * 256 + tid];
        go[tid] = fmaxf(s, 0.0f);
    }
    __syncthreads();
    // phase C: action = softmax(go @ actw + actb)
    if (tid < 8) {
        float s = actb[tid];
        for (int k = 0; k < 256; ++k) s += go[k] * actw[(size_t)k * 8 + tid];
        logits[tid] = s;
    }
    __syncthreads();
    if (tid == 0) {
        float mx = logits[0];
        for (int i = 1; i < 8; ++i) mx = fmaxf(mx, logits[i]);
        float ex[8], den = 0.0f;
        for (int i = 0; i < 8; ++i) { ex[i] = expf(logits[i] - mx); den += ex[i]; }
        float inv = 1.0f / den;
        for (int i = 0; i < 8; ++i) out_act[(size_t)g * 8 + i] = ex[i] * inv;
    }
}

// ---------------- workspace layout ----------------

constexpr size_t OFF_NODES_BF = 0;                                    // 8388608
constexpr size_t OFF_GLOB_BF  = OFF_NODES_BF + (size_t)TNN * TFN * 2; // 16384
constexpr size_t OFF_WACT = OFF_GLOB_BF + (size_t)TNG * TFG * 2;      // 1024*256*2
constexpr size_t OFF_WBT  = OFF_WACT + 1024 * 256 * 2;                // 512*64*2
constexpr size_t OFF_W1T  = OFF_WBT + 512 * 64 * 2;                   // 512*512*2
constexpr size_t OFF_W2T  = OFF_W1T + 512 * 512 * 2;                  // 256*512*2
constexpr size_t OFF_U0T  = OFF_W2T + 256 * 512 * 2;                  // 512*640*2
constexpr size_t OFF_U1T  = OFF_U0T + 512 * 640 * 2;                  // 256*512*2
constexpr size_t OFF_EMBT = OFF_U1T + 256 * 512 * 2;                  // 128*256*2
constexpr size_t OFF_AGGR = OFF_EMBT + 128 * 256 * 2;                 // 16384*256*2
constexpr size_t OFF_GDB  = OFF_AGGR + (size_t)TNN * 256 * 2;         // 64*512*4
constexpr size_t OFF_PAC  = OFF_GDB + 64 * 512 * 4;                   // 16384*1024*2
constexpr size_t OFF_MSG  = OFF_PAC + (size_t)TNN * 1024 * 2;         // full msg: TNE*256*2
constexpr size_t OFF_V    = OFF_MSG + (size_t)TNE * 256 * 2;          // chunked h1c/h2c
constexpr size_t SZ_HU1   = (size_t)TNN * 512 * 2;

extern "C" void kernel_launch(void* const* d_in, const int* in_sizes, int n_in,
                              void* d_out, int out_size, void* d_ws, size_t ws_size,
                              hipStream_t stream) {
    const float* nodes       = (const float*)d_in[0];
    const float* edge_attr   = (const float*)d_in[1];
    const float* global_attr = (const float*)d_in[2];
    const int*   edge_idx    = (const int*)d_in[3];
    const float* msg_w0 = (const float*)d_in[7];
    const float* msg_b0 = (const float*)d_in[8];
    const float* msg_w1 = (const float*)d_in[9];
    const float* msg_b1 = (const float*)d_in[10];
    const float* msg_w2 = (const float*)d_in[11];
    const float* msg_b2 = (const float*)d_in[12];
    const float* upd_w0 = (const float*)d_in[13];
    const float* upd_b0 = (const float*)d_in[14];
    const float* upd_w1 = (const float*)d_in[15];
    const float* upd_b1 = (const float*)d_in[16];
    const float* glob_w = (const float*)d_in[17];
    const float* glob_b = (const float*)d_in[18];
    const float* emb_w  = (const float*)d_in[19];
    const float* emb_b  = (const float*)d_in[20];
    const float* act_w  = (const float*)d_in[21];
    const float* act_b  = (const float*)d_in[22];

    const int* src = edge_idx;
    const int* tgt = edge_idx + TNE;

    char* ws = (char*)d_ws;
    u16* nodes_bf = (u16*)(ws + OFF_NODES_BF);
    u16* glob_bf  = (u16*)(ws + OFF_GLOB_BF);
    u16* WacT = (u16*)(ws + OFF_WACT);
    u16* WbT  = (u16*)(ws + OFF_WBT);
    u16* W1T  = (u16*)(ws + OFF_W1T);
    u16* W2T  = (u16*)(ws + OFF_W2T);
    u16* U0T  = (u16*)(ws + OFF_U0T);
    u16* U1T  = (u16*)(ws + OFF_U1T);
    u16* EmbT = (u16*)(ws + OFF_EMBT);
    u16* aggr = (u16*)(ws + OFF_AGGR);
    float* Gdb = (float*)(ws + OFF_GDB);
    u16* Pac  = (u16*)(ws + OFF_PAC);
    u16* msgc = (u16*)(ws + OFF_MSG);
    float* out = (float*)d_out;

    // chunk size: CH=32768 keeps the h1c/h2c working set L3-resident.
    size_t CH = 32768;
    while (CH > 2048 && OFF_V + CH * 2048 > ws_size) CH >>= 1;
    const int nchunk = (int)((size_t)TNE / CH);

    u16* h1c  = (u16*)(ws + OFF_V);
    u16* h2c  = (u16*)(ws + OFF_V + CH * 1024);
    u16* hu1  = (u16*)(ws + OFF_V);            // node phase (edge buffers dead)
    u16* h_bf = (u16*)(ws + OFF_AGGR);         // overlays aggr (dead after U0)

    // ---- setup ----
    cast_kernel<<<(TNN * TFN / 4 + 255) / 256, 256, 0, stream>>>(nodes, nodes_bf, TNN * TFN / 4);

    PrepTab tab;
    int ntiles = 0;
    {
        const float* Ws[8]  = {msg_w0, msg_w0, msg_w0, msg_w1, msg_w2, upd_w0, upd_w1, emb_w};
        int offs[8] = {(int)(OFF_WACT / 2), (int)(OFF_WACT / 2) + 131072, (int)(OFF_WBT / 2),
                       (int)(OFF_W1T / 2), (int)(OFF_W2T / 2), (int)(OFF_U0T / 2),
                       (int)(OFF_U1T / 2), (int)(OFF_EMBT / 2)};
        int nin[8]  = {512, 512, 512, 512, 256, 512, 256, 64};
        int nact[8] = {512, 512, 512, 512, 256, 512, 256, 64};
        int r0v[8]  = {0, 320, 256, 0, 0, 0, 0, 0};
        int ksub[8] = {256, 256, 64, 512, 512, 640, 512, 256};
        int npad[8] = {512, 512, 512, 512, 256, 512, 256, 128};
        int acc = 0;
        for (int i = 0; i < 8; ++i) {
            tab.W[i] = Ws[i]; tab.out_off[i] = offs[i]; tab.Nin[i] = nin[i];
            tab.Nact[i] = nact[i]; tab.r0[i] = r0v[i]; tab.Ksub[i] = ksub[i];
            tab.tkn[i] = ksub[i] / 64;
            tab.tile0[i] = acc;
            acc += (npad[i] / 64) * (ksub[i] / 64);
        }
        ntiles = acc;   // 288
    }
    prep_weights_kernel<<<ntiles, 256, 0, stream>>>(tab, (u16*)ws);
    gd_kernel<<<64, 256, 0, stream>>>(global_attr, msg_w0, msg_b0, Gdb, glob_bf);

    // Pac = nodes_bf @ [Wa | Wc]^T   (M=16384, N=1024, K=256)
    gemm_bt_kernel<256, 3, false, true><<<1024, 256, 0, stream>>>(nodes_bf, WacT, nullptr, Pac, 1024, 1024);

    // ---- edge pipeline (chunked for L3 residency); scatter once at the end ----
    for (int ci = 0; ci < nchunk; ++ci) {
        const int e0 = (int)(ci * CH);
        const int nwg = (int)(CH / 32);   // 4 * CH/128
        h1_fused_kernel<<<nwg, 256, 0, stream>>>(
            edge_attr, WbT, Pac, Gdb, src, tgt, h1c, e0);
        gemm_bt_kernel<512, 2, true, true><<<nwg, 256, 0, stream>>>(h1c, W1T, msg_b1, h2c, 512, 512);
        gemm_bt_kernel<512, 1, true, true><<<nwg / 2, 256, 0, stream>>>(
            h2c, W2T, msg_b2, msgc + (size_t)e0 * 256, 256, 256);
    }
    scatter_max_kernel<<<TNG * 4, 1024, 0, stream>>>(msgc, tgt, aggr);

    // ---- node update MLP (concat fused into U0 staging) ----
    gemm_u0_kernel<<<512, 256, 0, stream>>>(nodes_bf, aggr, glob_bf, U0T, upd_b0, hu1);
    gemm_bt_kernel<512, 1, true, true><<<256, 256, 0, stream>>>(hu1, U1T, upd_b1, h_bf, 256, 256);

    // ---- heads ----
    head_kernel<<<64, 256, 0, stream>>>(h_bf, global_attr, glob_w, glob_b,
                                        act_w, act_b, out + (size_t)TNN * 64);
    gemm_bt_kernel<256, 0, true, false><<<128, 256, 0, stream>>>(h_bf, EmbT, emb_b, out, 64, 64);

    (void)in_sizes; (void)n_in; (void)out_size;
}